// Round 1
// baseline (4851.756 us; speedup 1.0000x reference)
//
#include <hip/hip_runtime.h>
#include <cmath>

#define B_    4
#define S_    512
#define CIN_  512
#define H_    768
#define I_    1536
#define N_    16
#define R_    48
#define K_    4
#define L_    4
#define EPS_  1e-5f
#define MROWS (B_ * S_)   // 2048

__device__ __forceinline__ float siluf(float x) { return x / (1.f + expf(-x)); }
__device__ __forceinline__ float softplusf(float x) { return x > 20.f ? x : log1pf(expf(x)); }

// ---------------------------------------------------------------------------
// Generic tiled fp32 GEMM: C[M,N] = A[M,K] @ B[K,N], epilogues:
//   ep=0: none; ep=1: +bias[n]; ep=2: softplus(v + bias[n]); ep=3: C[m,n] += v
// 64x64 tile, BK=16, 256 threads, 4x4 microtile.
// ---------------------------------------------------------------------------
__global__ __launch_bounds__(256) void gemm_tiled(
    const float* __restrict__ A, const float* __restrict__ B,
    const float* __restrict__ bias, float* __restrict__ C,
    int M, int N, int Kd, int lda, int ldb, int ldc, int ep)
{
    __shared__ float As[16][64];
    __shared__ float Bs[16][65];
    const int tid  = threadIdx.x;
    const int row0 = blockIdx.y * 64;
    const int col0 = blockIdx.x * 64;
    const int tx = tid & 15, ty = tid >> 4;

    float acc[4][4] = {};

    for (int k0 = 0; k0 < Kd; k0 += 16) {
        // load A tile (64 rows x 16 k)
        for (int i = tid; i < 64 * 16; i += 256) {
            int m = i >> 4, k = i & 15;
            int gm = row0 + m, gk = k0 + k;
            As[k][m] = (gm < M && gk < Kd) ? A[(size_t)gm * lda + gk] : 0.f;
        }
        // load B tile (16 k x 64 cols)
        for (int i = tid; i < 16 * 64; i += 256) {
            int k = i >> 6, n = i & 63;
            int gk = k0 + k, gn = col0 + n;
            Bs[k][n] = (gk < Kd && gn < N) ? B[(size_t)gk * ldb + gn] : 0.f;
        }
        __syncthreads();
        #pragma unroll
        for (int k = 0; k < 16; ++k) {
            float a[4], b[4];
            #pragma unroll
            for (int i = 0; i < 4; ++i) a[i] = As[k][ty * 4 + i];
            #pragma unroll
            for (int j = 0; j < 4; ++j) b[j] = Bs[k][tx * 4 + j];
            #pragma unroll
            for (int i = 0; i < 4; ++i)
                #pragma unroll
                for (int j = 0; j < 4; ++j)
                    acc[i][j] = fmaf(a[i], b[j], acc[i][j]);
        }
        __syncthreads();
    }

    #pragma unroll
    for (int i = 0; i < 4; ++i) {
        int m = row0 + ty * 4 + i;
        if (m >= M) continue;
        #pragma unroll
        for (int j = 0; j < 4; ++j) {
            int n = col0 + tx * 4 + j;
            if (n >= N) continue;
            float v = acc[i][j];
            if (ep == 1)      v += bias[n];
            else if (ep == 2) v  = softplusf(v + bias[n]);
            else if (ep == 3) v += C[(size_t)m * ldc + n];
            C[(size_t)m * ldc + n] = v;
        }
    }
}

// ---------------------------------------------------------------------------
// RMSNorm over last dim (ncols), one block per row.
// ---------------------------------------------------------------------------
__global__ __launch_bounds__(256) void rmsnorm_kernel(
    const float* __restrict__ x, const float* __restrict__ w,
    float* __restrict__ out, int ncols)
{
    const int row = blockIdx.x;
    const float* xr = x + (size_t)row * ncols;
    float ss = 0.f;
    for (int c = threadIdx.x; c < ncols; c += 256) { float v = xr[c]; ss += v * v; }
    #pragma unroll
    for (int off = 32; off > 0; off >>= 1) ss += __shfl_down(ss, off, 64);
    __shared__ float red[4];
    __shared__ float stot;
    if ((threadIdx.x & 63) == 0) red[threadIdx.x >> 6] = ss;
    __syncthreads();
    if (threadIdx.x == 0) stot = red[0] + red[1] + red[2] + red[3];
    __syncthreads();
    const float scale = rsqrtf(stot / (float)ncols + EPS_);
    for (int c = threadIdx.x; c < ncols; c += 256)
        out[(size_t)row * ncols + c] = xr[c] * scale * w[c];
}

// ---------------------------------------------------------------------------
// Causal depthwise conv1d (K=4) + bias + SiLU.
// xz layout (B,S,2I); conv input = first I columns. Output xc (B,S,I).
// ---------------------------------------------------------------------------
__global__ __launch_bounds__(256) void conv_silu_kernel(
    const float* __restrict__ xz, const float* __restrict__ cw,
    const float* __restrict__ cb, float* __restrict__ xc)
{
    int idx = blockIdx.x * 256 + threadIdx.x;
    if (idx >= MROWS * I_) return;
    int i  = idx % I_;
    int bs = idx / I_;
    int s  = bs % S_;
    int b  = bs / S_;
    const float* base = xz + (size_t)b * S_ * (2 * I_) + i;
    float acc = cb[i];
    #pragma unroll
    for (int k = 0; k < K_; ++k) {
        int ss = s - (K_ - 1) + k;
        if (ss >= 0) acc = fmaf(cw[i * K_ + k], base[(size_t)ss * (2 * I_)], acc);
    }
    xc[idx] = siluf(acc);
}

// ---------------------------------------------------------------------------
// Selective scan. 16 lanes per (b,i) channel, one lane per state n.
// y[b,s,i] = (sum_n h_n * C_n + xc*D) * silu(z)
// ---------------------------------------------------------------------------
__global__ __launch_bounds__(256) void scan_kernel(
    const float* __restrict__ xc, const float* __restrict__ dt,
    const float* __restrict__ dbc, const float* __restrict__ xz,
    const float* __restrict__ A_log, const float* __restrict__ D,
    float* __restrict__ y)
{
    const int g  = threadIdx.x >> 4;       // channel group within block
    const int n  = threadIdx.x & 15;       // state index
    const int ch = blockIdx.x * 16 + g;    // 0..B*I-1
    const int b  = ch / I_;
    const int i  = ch % I_;

    const float a  = -expf(A_log[i * N_ + n]);
    const float Dv = D[i];
    float hst = 0.f;

    const float* dtp  = dt  + (size_t)b * S_ * I_ + i;
    const float* xcp  = xc  + (size_t)b * S_ * I_ + i;
    const float* dbcp = dbc + (size_t)b * S_ * 80;
    const float* zp   = xz  + (size_t)b * S_ * (2 * I_) + I_ + i;
    float*       yp   = y   + (size_t)b * S_ * I_ + i;

    for (int s = 0; s < S_; ++s) {
        float dtv = dtp[(size_t)s * I_];
        float xcv = xcp[(size_t)s * I_];
        float Bv  = dbcp[s * 80 + R_ + n];
        float Cv  = dbcp[s * 80 + R_ + N_ + n];
        hst = fmaf(expf(dtv * a), hst, dtv * xcv * Bv);
        float yv = hst * Cv;
        #pragma unroll
        for (int off = 8; off > 0; off >>= 1) yv += __shfl_xor(yv, off, 16);
        if (n == 0) {
            float zv = zp[(size_t)s * (2 * I_)];
            yp[(size_t)s * I_] = (yv + xcv * Dv) * siluf(zv);
        }
    }
}

// ---------------------------------------------------------------------------
extern "C" void kernel_launch(void* const* d_in, const int* in_sizes, int n_in,
                              void* d_out, int out_size, void* d_ws, size_t ws_size,
                              hipStream_t stream)
{
    const float* x     = (const float*)d_in[0];
    const float* W_in  = (const float*)d_in[1];
    const float* b_in  = (const float*)d_in[2];
    const float* norm_w= (const float*)d_in[3];
    const float* ipw   = (const float*)d_in[4];
    const float* cw    = (const float*)d_in[5];
    const float* cb    = (const float*)d_in[6];
    const float* xpw   = (const float*)d_in[7];
    const float* dpw   = (const float*)d_in[8];
    const float* dpb   = (const float*)d_in[9];
    const float* A_log = (const float*)d_in[10];
    const float* Dp    = (const float*)d_in[11];
    const float* opw   = (const float*)d_in[12];
    const float* nfw   = (const float*)d_in[13];
    float* out = (float*)d_out;

    float* ws   = (float*)d_ws;
    float* h    = ws;  ws += (size_t)MROWS * H_;
    float* u    = ws;  ws += (size_t)MROWS * H_;
    float* xzb  = ws;  ws += (size_t)MROWS * 2 * I_;
    float* xcb  = ws;  ws += (size_t)MROWS * I_;
    float* dbcb = ws;  ws += (size_t)MROWS * 80;
    float* dtb  = ws;  ws += (size_t)MROWS * I_;
    float* yb   = ws;  ws += (size_t)MROWS * I_;

    const dim3 blk(256);

    // h = x @ W_in + b_in
    gemm_tiled<<<dim3((H_ + 63) / 64, MROWS / 64), blk, 0, stream>>>(
        x, W_in, b_in, h, MROWS, H_, CIN_, CIN_, H_, H_, 1);

    for (int l = 0; l < L_; ++l) {
        // u = rmsnorm(h, norm_w[l])
        rmsnorm_kernel<<<MROWS, blk, 0, stream>>>(h, norm_w + l * H_, u, H_);
        // xz = u @ in_proj_w[l]
        gemm_tiled<<<dim3((2 * I_ + 63) / 64, MROWS / 64), blk, 0, stream>>>(
            u, ipw + (size_t)l * H_ * 2 * I_, nullptr, xzb,
            MROWS, 2 * I_, H_, H_, 2 * I_, 2 * I_, 0);
        // xc = silu(causal_dwconv(xz[:,:,:I]) + conv_b)
        conv_silu_kernel<<<(MROWS * I_ + 255) / 256, blk, 0, stream>>>(
            xzb, cw + l * I_ * K_, cb + l * I_, xcb);
        // dbc = xc @ x_proj_w[l]
        gemm_tiled<<<dim3((80 + 63) / 64, MROWS / 64), blk, 0, stream>>>(
            xcb, xpw + (size_t)l * I_ * 80, nullptr, dbcb,
            MROWS, 80, I_, I_, 80, 80, 0);
        // dt = softplus(dbc[:,:, :R] @ dt_proj_w[l] + dt_proj_b[l])
        gemm_tiled<<<dim3((I_ + 63) / 64, MROWS / 64), blk, 0, stream>>>(
            dbcb, dpw + (size_t)l * R_ * I_, dpb + l * I_, dtb,
            MROWS, I_, R_, 80, I_, I_, 2);
        // y = selective_scan(...) * silu(z)
        scan_kernel<<<(B_ * I_) / 16, blk, 0, stream>>>(
            xcb, dtb, dbcb, xzb, A_log + l * I_ * N_, Dp + l * I_, yb);
        // h = h + y @ out_proj_w[l]
        gemm_tiled<<<dim3((H_ + 63) / 64, MROWS / 64), blk, 0, stream>>>(
            yb, opw + (size_t)l * I_ * H_, nullptr, h,
            MROWS, H_, I_, I_, H_, H_, 3);
    }

    // out = rmsnorm(h, norm_f_w)
    rmsnorm_kernel<<<MROWS, blk, 0, stream>>>(h, nfw, out, H_);
}

// Round 2
// 3794.098 us; speedup vs baseline: 1.2788x; 1.2788x over previous
//
#include <hip/hip_runtime.h>
#include <cmath>

#define B_    4
#define S_    512
#define CIN_  512
#define H_    768
#define I_    1536
#define N_    16
#define R_    48
#define K_    4
#define L_    4
#define EPS_  1e-5f
#define MROWS (B_ * S_)   // 2048
#define C_    8           // scan chunks
#define T_    (S_ / C_)   // 64 steps per chunk

__device__ __forceinline__ float siluf(float x) { return x / (1.f + expf(-x)); }
__device__ __forceinline__ float softplusf(float x) { return x > 20.f ? x : log1pf(expf(x)); }

// ---------------------------------------------------------------------------
// Generic tiled fp32 GEMM: C[M,N] = A[M,K] @ B[K,N], epilogues:
//   ep=0: none; ep=1: +bias[n]; ep=2: softplus(v + bias[n]); ep=3: C[m,n] += v
// 64x64 tile, BK=16, 256 threads, 4x4 microtile.
// ---------------------------------------------------------------------------
__global__ __launch_bounds__(256) void gemm_tiled(
    const float* __restrict__ A, const float* __restrict__ B,
    const float* __restrict__ bias, float* __restrict__ C,
    int M, int N, int Kd, int lda, int ldb, int ldc, int ep)
{
    __shared__ float As[16][64];
    __shared__ float Bs[16][65];
    const int tid  = threadIdx.x;
    const int row0 = blockIdx.y * 64;
    const int col0 = blockIdx.x * 64;
    const int tx = tid & 15, ty = tid >> 4;

    float acc[4][4] = {};

    for (int k0 = 0; k0 < Kd; k0 += 16) {
        for (int i = tid; i < 64 * 16; i += 256) {
            int m = i >> 4, k = i & 15;
            int gm = row0 + m, gk = k0 + k;
            As[k][m] = (gm < M && gk < Kd) ? A[(size_t)gm * lda + gk] : 0.f;
        }
        for (int i = tid; i < 16 * 64; i += 256) {
            int k = i >> 6, n = i & 63;
            int gk = k0 + k, gn = col0 + n;
            Bs[k][n] = (gk < Kd && gn < N) ? B[(size_t)gk * ldb + gn] : 0.f;
        }
        __syncthreads();
        #pragma unroll
        for (int k = 0; k < 16; ++k) {
            float a[4], b[4];
            #pragma unroll
            for (int i = 0; i < 4; ++i) a[i] = As[k][ty * 4 + i];
            #pragma unroll
            for (int j = 0; j < 4; ++j) b[j] = Bs[k][tx * 4 + j];
            #pragma unroll
            for (int i = 0; i < 4; ++i)
                #pragma unroll
                for (int j = 0; j < 4; ++j)
                    acc[i][j] = fmaf(a[i], b[j], acc[i][j]);
        }
        __syncthreads();
    }

    #pragma unroll
    for (int i = 0; i < 4; ++i) {
        int m = row0 + ty * 4 + i;
        if (m >= M) continue;
        #pragma unroll
        for (int j = 0; j < 4; ++j) {
            int n = col0 + tx * 4 + j;
            if (n >= N) continue;
            float v = acc[i][j];
            if (ep == 1)      v += bias[n];
            else if (ep == 2) v  = softplusf(v + bias[n]);
            else if (ep == 3) v += C[(size_t)m * ldc + n];
            C[(size_t)m * ldc + n] = v;
        }
    }
}

// ---------------------------------------------------------------------------
// RMSNorm over last dim (ncols), one block per row.
// ---------------------------------------------------------------------------
__global__ __launch_bounds__(256) void rmsnorm_kernel(
    const float* __restrict__ x, const float* __restrict__ w,
    float* __restrict__ out, int ncols)
{
    const int row = blockIdx.x;
    const float* xr = x + (size_t)row * ncols;
    float ss = 0.f;
    for (int c = threadIdx.x; c < ncols; c += 256) { float v = xr[c]; ss += v * v; }
    #pragma unroll
    for (int off = 32; off > 0; off >>= 1) ss += __shfl_down(ss, off, 64);
    __shared__ float red[4];
    __shared__ float stot;
    if ((threadIdx.x & 63) == 0) red[threadIdx.x >> 6] = ss;
    __syncthreads();
    if (threadIdx.x == 0) stot = red[0] + red[1] + red[2] + red[3];
    __syncthreads();
    const float scale = rsqrtf(stot / (float)ncols + EPS_);
    for (int c = threadIdx.x; c < ncols; c += 256)
        out[(size_t)row * ncols + c] = xr[c] * scale * w[c];
}

// ---------------------------------------------------------------------------
// Causal depthwise conv1d (K=4) + bias + SiLU.
// ---------------------------------------------------------------------------
__global__ __launch_bounds__(256) void conv_silu_kernel(
    const float* __restrict__ xz, const float* __restrict__ cw,
    const float* __restrict__ cb, float* __restrict__ xc)
{
    int idx = blockIdx.x * 256 + threadIdx.x;
    if (idx >= MROWS * I_) return;
    int i  = idx % I_;
    int bs = idx / I_;
    int s  = bs % S_;
    int b  = bs / S_;
    const float* base = xz + (size_t)b * S_ * (2 * I_) + i;
    float acc = cb[i];
    #pragma unroll
    for (int k = 0; k < K_; ++k) {
        int ss = s - (K_ - 1) + k;
        if (ss >= 0) acc = fmaf(cw[i * K_ + k], base[(size_t)ss * (2 * I_)], acc);
    }
    xc[idx] = siluf(acc);
}

// ---------------------------------------------------------------------------
// Chunk-parallel selective scan.
// h_t = dA_t * h_{t-1} + dBx_t  is a linear recurrence -> 3-pass chunked scan.
// Pass 1: per (b,c,i,n): P = prod(dA) over chunk, hend = scan from h0=0.
// Layout of P/hend/Hstart: [B][C][I][N].
// ---------------------------------------------------------------------------
__global__ __launch_bounds__(256) void scan_pass1(
    const float* __restrict__ xc, const float* __restrict__ dt,
    const float* __restrict__ dbc, const float* __restrict__ A_log,
    float* __restrict__ P, float* __restrict__ hend)
{
    const int g   = threadIdx.x >> 4;
    const int n   = threadIdx.x & 15;
    const int gid = blockIdx.x * 16 + g;       // over B*C*I, i fastest
    const int i   = gid % I_;
    const int c   = (gid / I_) % C_;
    const int b   = gid / (I_ * C_);
    const float a = -expf(A_log[i * N_ + n]);
    const int s0  = c * T_;
    const float* dtp = dt  + ((size_t)b * S_ + s0) * I_ + i;
    const float* xcp = xc  + ((size_t)b * S_ + s0) * I_ + i;
    const float* dbp = dbc + ((size_t)b * S_ + s0) * 80 + R_ + n;
    float p = 1.f, h = 0.f;
    #pragma unroll 4
    for (int s = 0; s < T_; ++s) {
        float dtv = dtp[(size_t)s * I_];
        float xcv = xcp[(size_t)s * I_];
        float Bv  = dbp[s * 80];
        float dA  = expf(dtv * a);
        h = fmaf(dA, h, dtv * xcv * Bv);
        p *= dA;
    }
    size_t o = ((size_t)gid) * N_ + n;
    P[o] = p; hend[o] = h;
}

// Pass 2: per (b,i,n): H_c = P_c * H_{c-1} + hend_c; store chunk start states.
__global__ __launch_bounds__(256) void scan_pass2(
    const float* __restrict__ P, const float* __restrict__ hend,
    float* __restrict__ Hstart)
{
    int idx = blockIdx.x * 256 + threadIdx.x;   // over B*I*N
    if (idx >= B_ * I_ * N_) return;
    int n = idx & 15;
    int i = (idx >> 4) % I_;
    int b = idx / (I_ * N_);
    float H = 0.f;
    #pragma unroll
    for (int c = 0; c < C_; ++c) {
        size_t o = (((size_t)b * C_ + c) * I_ + i) * (size_t)N_ + n;
        Hstart[o] = H;
        H = fmaf(P[o], H, hend[o]);
    }
}

// Pass 3: re-run recurrence per chunk from corrected start state; emit y.
__global__ __launch_bounds__(256) void scan_pass3(
    const float* __restrict__ xc, const float* __restrict__ dt,
    const float* __restrict__ dbc, const float* __restrict__ xz,
    const float* __restrict__ A_log, const float* __restrict__ D,
    const float* __restrict__ Hstart, float* __restrict__ y)
{
    const int g   = threadIdx.x >> 4;
    const int n   = threadIdx.x & 15;
    const int gid = blockIdx.x * 16 + g;       // over B*C*I, i fastest
    const int i   = gid % I_;
    const int c   = (gid / I_) % C_;
    const int b   = gid / (I_ * C_);
    const float a  = -expf(A_log[i * N_ + n]);
    const float Dv = D[i];
    const int s0   = c * T_;
    const float* dtp = dt  + ((size_t)b * S_ + s0) * I_ + i;
    const float* xcp = xc  + ((size_t)b * S_ + s0) * I_ + i;
    const float* dbp = dbc + ((size_t)b * S_ + s0) * 80;
    const float* zp  = xz  + ((size_t)b * S_ + s0) * (2 * I_) + I_ + i;
    float*       yp  = y   + ((size_t)b * S_ + s0) * I_ + i;
    float h = Hstart[((size_t)gid) * N_ + n];
    for (int s = 0; s < T_; ++s) {
        float dtv = dtp[(size_t)s * I_];
        float xcv = xcp[(size_t)s * I_];
        float Bv  = dbp[s * 80 + R_ + n];
        float Cv  = dbp[s * 80 + R_ + N_ + n];
        float dA  = expf(dtv * a);
        h = fmaf(dA, h, dtv * xcv * Bv);
        float yv = h * Cv;
        #pragma unroll
        for (int off = 8; off > 0; off >>= 1) yv += __shfl_xor(yv, off, 16);
        if (n == 0) {
            float zv = zp[(size_t)s * (2 * I_)];
            yp[(size_t)s * I_] = (yv + xcv * Dv) * siluf(zv);
        }
    }
}

// ---------------------------------------------------------------------------
extern "C" void kernel_launch(void* const* d_in, const int* in_sizes, int n_in,
                              void* d_out, int out_size, void* d_ws, size_t ws_size,
                              hipStream_t stream)
{
    const float* x     = (const float*)d_in[0];
    const float* W_in  = (const float*)d_in[1];
    const float* b_in  = (const float*)d_in[2];
    const float* norm_w= (const float*)d_in[3];
    const float* ipw   = (const float*)d_in[4];
    const float* cw    = (const float*)d_in[5];
    const float* cb    = (const float*)d_in[6];
    const float* xpw   = (const float*)d_in[7];
    const float* dpw   = (const float*)d_in[8];
    const float* dpb   = (const float*)d_in[9];
    const float* A_log = (const float*)d_in[10];
    const float* Dp    = (const float*)d_in[11];
    const float* opw   = (const float*)d_in[12];
    const float* nfw   = (const float*)d_in[13];
    float* out = (float*)d_out;

    float* ws   = (float*)d_ws;
    float* h    = ws;  ws += (size_t)MROWS * H_;
    float* u    = ws;  ws += (size_t)MROWS * H_;
    float* xzb  = ws;  ws += (size_t)MROWS * 2 * I_;
    float* xcb  = ws;  ws += (size_t)MROWS * I_;
    float* dbcb = ws;  ws += (size_t)MROWS * 80;
    float* dtb  = ws;  ws += (size_t)MROWS * I_;
    float* yb   = ws;  ws += (size_t)MROWS * I_;
    float* Pb   = ws;  ws += (size_t)B_ * C_ * I_ * N_;
    float* heb  = ws;  ws += (size_t)B_ * C_ * I_ * N_;
    float* Hsb  = ws;  ws += (size_t)B_ * C_ * I_ * N_;

    const dim3 blk(256);

    // h = x @ W_in + b_in
    gemm_tiled<<<dim3((H_ + 63) / 64, MROWS / 64), blk, 0, stream>>>(
        x, W_in, b_in, h, MROWS, H_, CIN_, CIN_, H_, H_, 1);

    for (int l = 0; l < L_; ++l) {
        rmsnorm_kernel<<<MROWS, blk, 0, stream>>>(h, norm_w + l * H_, u, H_);
        gemm_tiled<<<dim3((2 * I_ + 63) / 64, MROWS / 64), blk, 0, stream>>>(
            u, ipw + (size_t)l * H_ * 2 * I_, nullptr, xzb,
            MROWS, 2 * I_, H_, H_, 2 * I_, 2 * I_, 0);
        conv_silu_kernel<<<(MROWS * I_ + 255) / 256, blk, 0, stream>>>(
            xzb, cw + l * I_ * K_, cb + l * I_, xcb);
        gemm_tiled<<<dim3((80 + 63) / 64, MROWS / 64), blk, 0, stream>>>(
            xcb, xpw + (size_t)l * I_ * 80, nullptr, dbcb,
            MROWS, 80, I_, I_, 80, 80, 0);
        gemm_tiled<<<dim3((I_ + 63) / 64, MROWS / 64), blk, 0, stream>>>(
            dbcb, dpw + (size_t)l * R_ * I_, dpb + l * I_, dtb,
            MROWS, I_, R_, 80, I_, I_, 2);
        // chunk-parallel selective scan
        scan_pass1<<<(B_ * C_ * I_ * 16) / 256, blk, 0, stream>>>(
            xcb, dtb, dbcb, A_log + l * I_ * N_, Pb, heb);
        scan_pass2<<<(B_ * I_ * N_ + 255) / 256, blk, 0, stream>>>(Pb, heb, Hsb);
        scan_pass3<<<(B_ * C_ * I_ * 16) / 256, blk, 0, stream>>>(
            xcb, dtb, dbcb, xzb, A_log + l * I_ * N_, Dp + l * I_, Hsb, yb);
        // h = h + y @ out_proj_w[l]
        gemm_tiled<<<dim3((H_ + 63) / 64, MROWS / 64), blk, 0, stream>>>(
            yb, opw + (size_t)l * I_ * H_, nullptr, h,
            MROWS, H_, I_, I_, H_, H_, 3);
    }

    rmsnorm_kernel<<<MROWS, blk, 0, stream>>>(h, nfw, out, H_);
}

// Round 3
// 1494.988 us; speedup vs baseline: 3.2453x; 2.5379x over previous
//
#include <hip/hip_runtime.h>
#include <cmath>

#define B_    4
#define S_    512
#define CIN_  512
#define H_    768
#define I_    1536
#define N_    16
#define R_    48
#define K_    4
#define L_    4
#define EPS_  1e-5f
#define MROWS (B_ * S_)   // 2048
#define C_    8           // scan chunks
#define T_    (S_ / C_)   // 64 steps per chunk

typedef __attribute__((ext_vector_type(8))) short bf16x8;
typedef __attribute__((ext_vector_type(4))) float f32x4;

__device__ __forceinline__ float siluf(float x) { return x / (1.f + expf(-x)); }
__device__ __forceinline__ float softplusf(float x) { return x > 20.f ? x : log1pf(expf(x)); }
__device__ __forceinline__ short f2bf(float f) {
    union { float f; unsigned u; } v; v.f = f;
    unsigned r = v.u + 0x7fff + ((v.u >> 16) & 1);
    return (short)(r >> 16);
}

#define GLOAD16(g, l) __builtin_amdgcn_global_load_lds( \
    (const __attribute__((address_space(1))) void*)(g), \
    (__attribute__((address_space(3))) void*)(l), 16, 0, 0)

// ---------------------------------------------------------------------------
// bf16 MFMA GEMM (m97 structure): C[M,N] = A[M,K] @ Bt[N,K]^T
// 128x128 tile, BK=32, 256 threads = 4 waves (2x2), 4x4 frags of 16x16x32.
// ep: 0 none; 1 +bias; 2 softplus(v+bias); 3 C += v.  Cb: optional bf16 dup.
// M multiple of 128; Kd multiple of 32; Bt has >= ceil(N/128)*128 valid rows.
// ---------------------------------------------------------------------------
__global__ __launch_bounds__(256) void gemm_mfma(
    const short* __restrict__ A, const short* __restrict__ Bt,
    const float* __restrict__ bias, float* __restrict__ C,
    short* __restrict__ Cb,
    int M, int N, int Kd, int lda, int ldb, int ldc, int ep)
{
    __shared__ __align__(16) short Asl[128 * 32];
    __shared__ __align__(16) short Bsl[128 * 32];
    const int tid = threadIdx.x;
    const int ln  = tid & 63;
    const int wv  = tid >> 6;
    const int wm  = wv >> 1, wn = wv & 1;
    const int row0 = blockIdx.y * 128;
    const int col0 = blockIdx.x * 128;

    f32x4 acc[4][4];
    #pragma unroll
    for (int i = 0; i < 4; ++i)
        #pragma unroll
        for (int j = 0; j < 4; ++j) acc[i][j] = (f32x4){0.f, 0.f, 0.f, 0.f};

    // staging: 512 chunks of 16B per operand; chunk c -> row c>>2, kpart c&3
    const int c0 = tid, c1 = tid + 256;
    const short* ga0 = A  + (size_t)(row0 + (c0 >> 2)) * lda + (c0 & 3) * 8;
    const short* ga1 = A  + (size_t)(row0 + (c1 >> 2)) * lda + (c1 & 3) * 8;
    const short* gb0 = Bt + (size_t)(col0 + (c0 >> 2)) * ldb + (c0 & 3) * 8;
    const short* gb1 = Bt + (size_t)(col0 + (c1 >> 2)) * ldb + (c1 & 3) * 8;
    short* la0 = &Asl[(wv * 64) * 8];          // wave-uniform LDS bases
    short* la1 = &Asl[(256 + wv * 64) * 8];
    short* lb0 = &Bsl[(wv * 64) * 8];
    short* lb1 = &Bsl[(256 + wv * 64) * 8];

    const int lrow = ln & 15;
    const int lk   = (ln >> 4) * 8;

    for (int k0 = 0; k0 < Kd; k0 += 32) {
        GLOAD16(ga0 + k0, la0);
        GLOAD16(ga1 + k0, la1);
        GLOAD16(gb0 + k0, lb0);
        GLOAD16(gb1 + k0, lb1);
        __syncthreads();
        bf16x8 af[4], bfr[4];
        #pragma unroll
        for (int fm = 0; fm < 4; ++fm)
            af[fm] = *(const bf16x8*)&Asl[(wm * 64 + fm * 16 + lrow) * 32 + lk];
        #pragma unroll
        for (int fn = 0; fn < 4; ++fn)
            bfr[fn] = *(const bf16x8*)&Bsl[(wn * 64 + fn * 16 + lrow) * 32 + lk];
        #pragma unroll
        for (int fm = 0; fm < 4; ++fm)
            #pragma unroll
            for (int fn = 0; fn < 4; ++fn)
                acc[fm][fn] = __builtin_amdgcn_mfma_f32_16x16x32_bf16(
                    af[fm], bfr[fn], acc[fm][fn], 0, 0, 0);
        __syncthreads();
    }

    // epilogue: D layout col = ln&15, row = (ln>>4)*4 + r
    const int erow = (ln >> 4) * 4;
    const int ecol = ln & 15;
    #pragma unroll
    for (int fm = 0; fm < 4; ++fm) {
        #pragma unroll
        for (int fn = 0; fn < 4; ++fn) {
            int gn = col0 + wn * 64 + fn * 16 + ecol;
            if (gn >= N) continue;
            #pragma unroll
            for (int r = 0; r < 4; ++r) {
                int gm = row0 + wm * 64 + fm * 16 + erow + r;
                float v = acc[fm][fn][r];
                size_t o = (size_t)gm * ldc + gn;
                if (ep == 1)      v += bias[gn];
                else if (ep == 2) v  = softplusf(v + bias[gn]);
                else if (ep == 3) v += C[o];
                C[o] = v;
                if (Cb) Cb[o] = f2bf(v);
            }
        }
    }
}

// ---------------------------------------------------------------------------
// Weight transpose + fp32->bf16: out[Npad][Kpad] = in[K][N]^T, zero-padded.
// ---------------------------------------------------------------------------
__global__ __launch_bounds__(256) void wtrans(
    const float* __restrict__ in, short* __restrict__ out,
    int Kd, int Nn, int Kpad, int Npad)
{
    __shared__ float t[32][33];
    const int n0 = blockIdx.x * 32, k0 = blockIdx.y * 32;
    const int tx = threadIdx.x, ty = threadIdx.y;
    #pragma unroll
    for (int j = 0; j < 32; j += 8) {
        int k = k0 + ty + j, n = n0 + tx;
        t[ty + j][tx] = (k < Kd && n < Nn) ? in[(size_t)k * Nn + n] : 0.f;
    }
    __syncthreads();
    #pragma unroll
    for (int j = 0; j < 32; j += 8) {
        int np = n0 + ty + j, kp = k0 + tx;
        if (np < Npad && kp < Kpad) out[(size_t)np * Kpad + kp] = f2bf(t[tx][ty + j]);
    }
}

// cast fp32 -> bf16, 4 elems/thread
__global__ __launch_bounds__(256) void cast_bf16(
    const float* __restrict__ in, short* __restrict__ out, int n4)
{
    int i = blockIdx.x * 256 + threadIdx.x;
    if (i >= n4) return;
    float4 v = ((const float4*)in)[i];
    out[i * 4 + 0] = f2bf(v.x); out[i * 4 + 1] = f2bf(v.y);
    out[i * 4 + 2] = f2bf(v.z); out[i * 4 + 3] = f2bf(v.w);
}

// ---------------------------------------------------------------------------
// RMSNorm, bf16 output (feeds GEMM A operand).
// ---------------------------------------------------------------------------
__global__ __launch_bounds__(256) void rmsnorm_bf16(
    const float* __restrict__ x, const float* __restrict__ w,
    short* __restrict__ out, int ncols)
{
    const int row = blockIdx.x;
    const float* xr = x + (size_t)row * ncols;
    float ss = 0.f;
    for (int c = threadIdx.x; c < ncols; c += 256) { float v = xr[c]; ss += v * v; }
    #pragma unroll
    for (int off = 32; off > 0; off >>= 1) ss += __shfl_down(ss, off, 64);
    __shared__ float red[4];
    __shared__ float stot;
    if ((threadIdx.x & 63) == 0) red[threadIdx.x >> 6] = ss;
    __syncthreads();
    if (threadIdx.x == 0) stot = red[0] + red[1] + red[2] + red[3];
    __syncthreads();
    const float scale = rsqrtf(stot / (float)ncols + EPS_);
    for (int c = threadIdx.x; c < ncols; c += 256)
        out[(size_t)row * ncols + c] = f2bf(xr[c] * scale * w[c]);
}

__global__ __launch_bounds__(256) void rmsnorm_f32(
    const float* __restrict__ x, const float* __restrict__ w,
    float* __restrict__ out, int ncols)
{
    const int row = blockIdx.x;
    const float* xr = x + (size_t)row * ncols;
    float ss = 0.f;
    for (int c = threadIdx.x; c < ncols; c += 256) { float v = xr[c]; ss += v * v; }
    #pragma unroll
    for (int off = 32; off > 0; off >>= 1) ss += __shfl_down(ss, off, 64);
    __shared__ float red[4];
    __shared__ float stot;
    if ((threadIdx.x & 63) == 0) red[threadIdx.x >> 6] = ss;
    __syncthreads();
    if (threadIdx.x == 0) stot = red[0] + red[1] + red[2] + red[3];
    __syncthreads();
    const float scale = rsqrtf(stot / (float)ncols + EPS_);
    for (int c = threadIdx.x; c < ncols; c += 256)
        out[(size_t)row * ncols + c] = xr[c] * scale * w[c];
}

// ---------------------------------------------------------------------------
// Causal depthwise conv1d (K=4) + bias + SiLU; fp32 + bf16 outputs.
// ---------------------------------------------------------------------------
__global__ __launch_bounds__(256) void conv_silu_kernel(
    const float* __restrict__ xz, const float* __restrict__ cw,
    const float* __restrict__ cb, float* __restrict__ xc,
    short* __restrict__ xcb16)
{
    int idx = blockIdx.x * 256 + threadIdx.x;
    if (idx >= MROWS * I_) return;
    int i  = idx % I_;
    int bs = idx / I_;
    int s  = bs % S_;
    int b  = bs / S_;
    const float* base = xz + (size_t)b * S_ * (2 * I_) + i;
    float acc = cb[i];
    #pragma unroll
    for (int k = 0; k < K_; ++k) {
        int ss = s - (K_ - 1) + k;
        if (ss >= 0) acc = fmaf(cw[i * K_ + k], base[(size_t)ss * (2 * I_)], acc);
    }
    float v = siluf(acc);
    xc[idx] = v;
    xcb16[idx] = f2bf(v);
}

// ---------------------------------------------------------------------------
// Chunk-parallel selective scan (3 passes).
// ---------------------------------------------------------------------------
__global__ __launch_bounds__(256) void scan_pass1(
    const float* __restrict__ xc, const float* __restrict__ dt,
    const float* __restrict__ dbc, const float* __restrict__ A_log,
    float* __restrict__ P, float* __restrict__ hend)
{
    const int g   = threadIdx.x >> 4;
    const int n   = threadIdx.x & 15;
    const int gid = blockIdx.x * 16 + g;       // over B*C*I, i fastest
    const int i   = gid % I_;
    const int c   = (gid / I_) % C_;
    const int b   = gid / (I_ * C_);
    const float a = -expf(A_log[i * N_ + n]);
    const int s0  = c * T_;
    const float* dtp = dt  + ((size_t)b * S_ + s0) * I_ + i;
    const float* xcp = xc  + ((size_t)b * S_ + s0) * I_ + i;
    const float* dbp = dbc + ((size_t)b * S_ + s0) * 80 + R_ + n;
    float p = 1.f, h = 0.f;
    #pragma unroll 4
    for (int s = 0; s < T_; ++s) {
        float dtv = dtp[(size_t)s * I_];
        float xcv = xcp[(size_t)s * I_];
        float Bv  = dbp[s * 80];
        float dA  = expf(dtv * a);
        h = fmaf(dA, h, dtv * xcv * Bv);
        p *= dA;
    }
    size_t o = ((size_t)gid) * N_ + n;
    P[o] = p; hend[o] = h;
}

__global__ __launch_bounds__(256) void scan_pass2(
    const float* __restrict__ P, const float* __restrict__ hend,
    float* __restrict__ Hstart)
{
    int idx = blockIdx.x * 256 + threadIdx.x;   // over B*I*N
    if (idx >= B_ * I_ * N_) return;
    int n = idx & 15;
    int i = (idx >> 4) % I_;
    int b = idx / (I_ * N_);
    float H = 0.f;
    #pragma unroll
    for (int c = 0; c < C_; ++c) {
        size_t o = (((size_t)b * C_ + c) * I_ + i) * (size_t)N_ + n;
        Hstart[o] = H;
        H = fmaf(P[o], H, hend[o]);
    }
}

__global__ __launch_bounds__(256) void scan_pass3(
    const float* __restrict__ xc, const float* __restrict__ dt,
    const float* __restrict__ dbc, const float* __restrict__ xz,
    const float* __restrict__ A_log, const float* __restrict__ D,
    const float* __restrict__ Hstart, short* __restrict__ y16)
{
    const int g   = threadIdx.x >> 4;
    const int n   = threadIdx.x & 15;
    const int gid = blockIdx.x * 16 + g;       // over B*C*I, i fastest
    const int i   = gid % I_;
    const int c   = (gid / I_) % C_;
    const int b   = gid / (I_ * C_);
    const float a  = -expf(A_log[i * N_ + n]);
    const float Dv = D[i];
    const int s0   = c * T_;
    const float* dtp = dt  + ((size_t)b * S_ + s0) * I_ + i;
    const float* xcp = xc  + ((size_t)b * S_ + s0) * I_ + i;
    const float* dbp = dbc + ((size_t)b * S_ + s0) * 80;
    const float* zp  = xz  + ((size_t)b * S_ + s0) * (2 * I_) + I_ + i;
    short*       yp  = y16 + ((size_t)b * S_ + s0) * I_ + i;
    float h = Hstart[((size_t)gid) * N_ + n];
    for (int s = 0; s < T_; ++s) {
        float dtv = dtp[(size_t)s * I_];
        float xcv = xcp[(size_t)s * I_];
        float Bv  = dbp[s * 80 + R_ + n];
        float Cv  = dbp[s * 80 + R_ + N_ + n];
        float dA  = expf(dtv * a);
        h = fmaf(dA, h, dtv * xcv * Bv);
        float yv = h * Cv;
        #pragma unroll
        for (int off = 8; off > 0; off >>= 1) yv += __shfl_xor(yv, off, 16);
        if (n == 0) {
            float zv = zp[(size_t)s * (2 * I_)];
            yp[(size_t)s * I_] = f2bf((yv + xcv * Dv) * siluf(zv));
        }
    }
}

// ---------------------------------------------------------------------------
extern "C" void kernel_launch(void* const* d_in, const int* in_sizes, int n_in,
                              void* d_out, int out_size, void* d_ws, size_t ws_size,
                              hipStream_t stream)
{
    const float* x     = (const float*)d_in[0];
    const float* W_in  = (const float*)d_in[1];
    const float* b_in  = (const float*)d_in[2];
    const float* norm_w= (const float*)d_in[3];
    const float* ipw   = (const float*)d_in[4];
    const float* cw    = (const float*)d_in[5];
    const float* cb    = (const float*)d_in[6];
    const float* xpw   = (const float*)d_in[7];
    const float* dpw   = (const float*)d_in[8];
    const float* dpb   = (const float*)d_in[9];
    const float* A_log = (const float*)d_in[10];
    const float* Dp    = (const float*)d_in[11];
    const float* opw   = (const float*)d_in[12];
    const float* nfw   = (const float*)d_in[13];
    float* out = (float*)d_out;

    // fp32 scratch
    float* wsf  = (float*)d_ws;
    float* h    = wsf;  wsf += (size_t)MROWS * H_;
    float* xzb  = wsf;  wsf += (size_t)MROWS * 2 * I_;
    float* xcb  = wsf;  wsf += (size_t)MROWS * I_;
    float* dbcb = wsf;  wsf += (size_t)MROWS * 80;
    float* dtb  = wsf;  wsf += (size_t)MROWS * I_;
    float* Pb   = wsf;  wsf += (size_t)B_ * C_ * I_ * N_;
    float* heb  = wsf;  wsf += (size_t)B_ * C_ * I_ * N_;
    float* Hsb  = wsf;  wsf += (size_t)B_ * C_ * I_ * N_;
    // bf16 scratch
    short* wss   = (short*)wsf;
    short* x_bf  = wss;  wss += (size_t)MROWS * CIN_;
    short* u_bf  = wss;  wss += (size_t)MROWS * H_;
    short* xc_bf = wss;  wss += (size_t)MROWS * I_;
    short* dbc_bf= wss;  wss += (size_t)MROWS * 80;
    short* y_bf  = wss;  wss += (size_t)MROWS * I_;
    short* WinT  = wss;  wss += (size_t)H_ * CIN_;
    short* ipwT  = wss;  wss += (size_t)L_ * 2 * I_ * H_;
    short* xpwT  = wss;  wss += (size_t)L_ * 128 * I_;
    short* dpwT  = wss;  wss += (size_t)L_ * I_ * 64;
    short* opwT  = wss;  wss += (size_t)L_ * H_ * I_;

    const dim3 blk(256);
    const dim3 tblk(32, 8);

    // one-time conversions
    cast_bf16<<<(MROWS * CIN_ / 4 + 255) / 256, blk, 0, stream>>>(x, x_bf, MROWS * CIN_ / 4);
    wtrans<<<dim3(H_ / 32, CIN_ / 32), tblk, 0, stream>>>(W_in, WinT, CIN_, H_, CIN_, H_);
    for (int l = 0; l < L_; ++l) {
        wtrans<<<dim3(2 * I_ / 32, H_ / 32), tblk, 0, stream>>>(
            ipw + (size_t)l * H_ * 2 * I_, ipwT + (size_t)l * 2 * I_ * H_, H_, 2 * I_, H_, 2 * I_);
        wtrans<<<dim3(128 / 32, I_ / 32), tblk, 0, stream>>>(
            xpw + (size_t)l * I_ * 80, xpwT + (size_t)l * 128 * I_, I_, 80, I_, 128);
        wtrans<<<dim3(I_ / 32, 64 / 32), tblk, 0, stream>>>(
            dpw + (size_t)l * R_ * I_, dpwT + (size_t)l * I_ * 64, R_, I_, 64, I_);
        wtrans<<<dim3(H_ / 32, I_ / 32), tblk, 0, stream>>>(
            opw + (size_t)l * I_ * H_, opwT + (size_t)l * H_ * I_, I_, H_, I_, H_);
    }

    // h = x @ W_in + b_in
    gemm_mfma<<<dim3(H_ / 128, MROWS / 128), blk, 0, stream>>>(
        x_bf, WinT, b_in, h, nullptr, MROWS, H_, CIN_, CIN_, CIN_, H_, 1);

    for (int l = 0; l < L_; ++l) {
        rmsnorm_bf16<<<MROWS, blk, 0, stream>>>(h, norm_w + l * H_, u_bf, H_);
        // xz = u @ in_proj_w
        gemm_mfma<<<dim3(2 * I_ / 128, MROWS / 128), blk, 0, stream>>>(
            u_bf, ipwT + (size_t)l * 2 * I_ * H_, nullptr, xzb, nullptr,
            MROWS, 2 * I_, H_, H_, H_, 2 * I_, 0);
        conv_silu_kernel<<<(MROWS * I_ + 255) / 256, blk, 0, stream>>>(
            xzb, cw + l * I_ * K_, cb + l * I_, xcb, xc_bf);
        // dbc = xc @ x_proj_w   (N=80 in a 128-tile; xpwT padded)
        gemm_mfma<<<dim3(1, MROWS / 128), blk, 0, stream>>>(
            xc_bf, xpwT + (size_t)l * 128 * I_, nullptr, dbcb, dbc_bf,
            MROWS, 80, I_, I_, I_, 80, 0);
        // dt = softplus(dbc[:, :48] @ dt_proj_w + b)   (K padded 48->64)
        gemm_mfma<<<dim3(I_ / 128, MROWS / 128), blk, 0, stream>>>(
            dbc_bf, dpwT + (size_t)l * I_ * 64, dpb + l * I_, dtb, nullptr,
            MROWS, I_, 64, 80, 64, I_, 2);
        // chunked selective scan
        scan_pass1<<<(B_ * C_ * I_ * 16) / 256, blk, 0, stream>>>(
            xcb, dtb, dbcb, A_log + l * I_ * N_, Pb, heb);
        scan_pass2<<<(B_ * I_ * N_ + 255) / 256, blk, 0, stream>>>(Pb, heb, Hsb);
        scan_pass3<<<(B_ * C_ * I_ * 16) / 256, blk, 0, stream>>>(
            xcb, dtb, dbcb, xzb, A_log + l * I_ * N_, Dp + l * I_, Hsb, y_bf);
        // h += y @ out_proj_w
        gemm_mfma<<<dim3(H_ / 128, MROWS / 128), blk, 0, stream>>>(
            y_bf, opwT + (size_t)l * H_ * I_, nullptr, h, nullptr,
            MROWS, H_, I_, I_, I_, H_, 3);
    }

    rmsnorm_f32<<<MROWS, blk, 0, stream>>>(h, nfw, out, H_);
}

// Round 5
// 1191.742 us; speedup vs baseline: 4.0711x; 1.2545x over previous
//
#include <hip/hip_runtime.h>
#include <cmath>

#define B_    4
#define S_    512
#define CIN_  512
#define H_    768
#define I_    1536
#define N_    16
#define R_    48
#define K_    4
#define L_    4
#define EPS_  1e-5f
#define MROWS (B_ * S_)   // 2048
#define C_    8           // scan chunks
#define T_    (S_ / C_)   // 64 steps per chunk

typedef __attribute__((ext_vector_type(8))) short bf16x8;
typedef __attribute__((ext_vector_type(4))) float f32x4;

__device__ __forceinline__ float siluf(float x) { return x / (1.f + expf(-x)); }
__device__ __forceinline__ float softplusf(float x) { return x > 20.f ? x : log1pf(expf(x)); }
__device__ __forceinline__ short f2bf(float f) {
    union { float f; unsigned u; } v; v.f = f;
    unsigned r = v.u + 0x7fff + ((v.u >> 16) & 1);
    return (short)(r >> 16);
}

#define GLOAD16(g, l) __builtin_amdgcn_global_load_lds( \
    (const __attribute__((address_space(1))) void*)(g), \
    (__attribute__((address_space(3))) void*)(l), 16, 0, 0)

// ---------------------------------------------------------------------------
// bf16 MFMA GEMM: C[M,N] = A[M,K] @ Bt[N,K]^T
// 128x128 tile, BK=32, 256 threads = 4 waves (2x2), 4x4 frags of 16x16x32.
// gridDim.z > 1: split-K; block z handles K chunk [z*Kd/Z, (z+1)*Kd/Z),
//   writes raw partial to C + z*M*ldc (ep ignored).
// gridDim.z == 1: ep: 0 none; 1 +bias; 2 softplus(v+bias); 3 C += v.
// ---------------------------------------------------------------------------
__global__ __launch_bounds__(256) void gemm_mfma(
    const short* __restrict__ A, const short* __restrict__ Bt,
    const float* __restrict__ bias, float* __restrict__ C,
    int M, int N, int Kd, int lda, int ldb, int ldc, int ep)
{
    __shared__ __align__(16) short Asl[128 * 32];
    __shared__ __align__(16) short Bsl[128 * 32];
    const int tid = threadIdx.x;
    const int ln  = tid & 63;
    const int wv  = tid >> 6;
    const int wm  = wv >> 1, wn = wv & 1;
    const int row0 = blockIdx.y * 128;
    const int col0 = blockIdx.x * 128;
    const int nz   = gridDim.z;
    const int kchunk = Kd / nz;
    const int kbeg   = blockIdx.z * kchunk;

    f32x4 acc[4][4];
    #pragma unroll
    for (int i = 0; i < 4; ++i)
        #pragma unroll
        for (int j = 0; j < 4; ++j) acc[i][j] = (f32x4){0.f, 0.f, 0.f, 0.f};

    const int c0 = tid, c1 = tid + 256;
    const short* ga0 = A  + (size_t)(row0 + (c0 >> 2)) * lda + (c0 & 3) * 8;
    const short* ga1 = A  + (size_t)(row0 + (c1 >> 2)) * lda + (c1 & 3) * 8;
    const short* gb0 = Bt + (size_t)(col0 + (c0 >> 2)) * ldb + (c0 & 3) * 8;
    const short* gb1 = Bt + (size_t)(col0 + (c1 >> 2)) * ldb + (c1 & 3) * 8;
    short* la0 = &Asl[(wv * 64) * 8];
    short* la1 = &Asl[(256 + wv * 64) * 8];
    short* lb0 = &Bsl[(wv * 64) * 8];
    short* lb1 = &Bsl[(256 + wv * 64) * 8];

    const int lrow = ln & 15;
    const int lk   = (ln >> 4) * 8;

    for (int k0 = kbeg; k0 < kbeg + kchunk; k0 += 32) {
        GLOAD16(ga0 + k0, la0);
        GLOAD16(ga1 + k0, la1);
        GLOAD16(gb0 + k0, lb0);
        GLOAD16(gb1 + k0, lb1);
        __syncthreads();
        bf16x8 af[4], bfr[4];
        #pragma unroll
        for (int fm = 0; fm < 4; ++fm)
            af[fm] = *(const bf16x8*)&Asl[(wm * 64 + fm * 16 + lrow) * 32 + lk];
        #pragma unroll
        for (int fn = 0; fn < 4; ++fn)
            bfr[fn] = *(const bf16x8*)&Bsl[(wn * 64 + fn * 16 + lrow) * 32 + lk];
        #pragma unroll
        for (int fm = 0; fm < 4; ++fm)
            #pragma unroll
            for (int fn = 0; fn < 4; ++fn)
                acc[fm][fn] = __builtin_amdgcn_mfma_f32_16x16x32_bf16(
                    af[fm], bfr[fn], acc[fm][fn], 0, 0, 0);
        __syncthreads();
    }

    const int erow = (ln >> 4) * 4;
    const int ecol = ln & 15;
    const size_t zoff = (size_t)blockIdx.z * M * ldc;
    #pragma unroll
    for (int fm = 0; fm < 4; ++fm) {
        #pragma unroll
        for (int fn = 0; fn < 4; ++fn) {
            int gn = col0 + wn * 64 + fn * 16 + ecol;
            if (gn >= N) continue;
            #pragma unroll
            for (int r = 0; r < 4; ++r) {
                int gm = row0 + wm * 64 + fm * 16 + erow + r;
                float v = acc[fm][fn][r];
                size_t o = (size_t)gm * ldc + gn;
                if (nz > 1) { C[zoff + o] = v; continue; }
                if (ep == 1)      v += bias[gn];
                else if (ep == 2) v  = softplusf(v + bias[gn]);
                else if (ep == 3) v += C[o];
                C[o] = v;
            }
        }
    }
}

// ---------------------------------------------------------------------------
// Split-K reduce: C[idx] <- sum_z part[idx + z*strideZ]  (+bias / +C per mode)
// mode 0: plain; 1: + bias[idx % ldc]; 2: + C[idx]
// ---------------------------------------------------------------------------
__global__ __launch_bounds__(256) void reduce_parts(
    const float* __restrict__ part, float* __restrict__ C,
    const float* __restrict__ bias, int total, int ldc, int nz, int mode)
{
    int idx = blockIdx.x * 256 + threadIdx.x;
    if (idx >= total) return;
    size_t strideZ = (size_t)total;
    float s = 0.f;
    for (int z = 0; z < nz; ++z) s += part[idx + z * strideZ];
    if (mode == 1)      s += bias[idx % ldc];
    else if (mode == 2) s += C[idx];
    C[idx] = s;
}

// ---------------------------------------------------------------------------
// dt_proj fused kernel: dt[m][n] = softplus(sum_k dbc[m][k] * dpw[k][n] + dpb[n])
// K=48, fp32. 64x64 tile, 256 threads, 4x4 per thread.
// ---------------------------------------------------------------------------
__global__ __launch_bounds__(256) void dt_kernel(
    const float* __restrict__ dbc, const float* __restrict__ dpw,
    const float* __restrict__ dpb, float* __restrict__ dt)
{
    __shared__ float As[64][49];
    __shared__ float Bs[48][65];
    const int tid  = threadIdx.x;
    const int row0 = blockIdx.y * 64;
    const int col0 = blockIdx.x * 64;
    for (int idx = tid; idx < 64 * 48; idx += 256) {
        int m = idx / 48, k = idx - m * 48;
        As[m][k] = dbc[(size_t)(row0 + m) * 80 + k];
    }
    for (int idx = tid; idx < 48 * 64; idx += 256) {
        int k = idx >> 6, n = idx & 63;
        Bs[k][n] = dpw[(size_t)k * I_ + col0 + n];
    }
    __syncthreads();
    const int tx = tid & 15, ty = tid >> 4;
    float acc[4][4] = {};
    #pragma unroll
    for (int k = 0; k < 48; ++k) {
        float a[4], b[4];
        #pragma unroll
        for (int i = 0; i < 4; ++i) a[i] = As[ty * 4 + i][k];
        #pragma unroll
        for (int j = 0; j < 4; ++j) b[j] = Bs[k][tx * 4 + j];
        #pragma unroll
        for (int i = 0; i < 4; ++i)
            #pragma unroll
            for (int j = 0; j < 4; ++j)
                acc[i][j] = fmaf(a[i], b[j], acc[i][j]);
    }
    #pragma unroll
    for (int i = 0; i < 4; ++i) {
        int gm = row0 + ty * 4 + i;
        #pragma unroll
        for (int j = 0; j < 4; ++j) {
            int gn = col0 + tx * 4 + j;
            dt[(size_t)gm * I_ + gn] = softplusf(acc[i][j] + dpb[gn]);
        }
    }
}

// ---------------------------------------------------------------------------
// Weight transpose + fp32->bf16: out[Npad][Kpad] = in[K][N]^T, zero-padded.
// ---------------------------------------------------------------------------
__global__ __launch_bounds__(256) void wtrans(
    const float* __restrict__ in, short* __restrict__ out,
    int Kd, int Nn, int Kpad, int Npad)
{
    __shared__ float t[32][33];
    const int n0 = blockIdx.x * 32, k0 = blockIdx.y * 32;
    const int tx = threadIdx.x, ty = threadIdx.y;
    #pragma unroll
    for (int j = 0; j < 32; j += 8) {
        int k = k0 + ty + j, n = n0 + tx;
        t[ty + j][tx] = (k < Kd && n < Nn) ? in[(size_t)k * Nn + n] : 0.f;
    }
    __syncthreads();
    #pragma unroll
    for (int j = 0; j < 32; j += 8) {
        int np = n0 + ty + j, kp = k0 + tx;
        if (np < Npad && kp < Kpad) out[(size_t)np * Kpad + kp] = f2bf(t[tx][ty + j]);
    }
}

__global__ __launch_bounds__(256) void cast_bf16(
    const float* __restrict__ in, short* __restrict__ out, int n4)
{
    int i = blockIdx.x * 256 + threadIdx.x;
    if (i >= n4) return;
    float4 v = ((const float4*)in)[i];
    out[i * 4 + 0] = f2bf(v.x); out[i * 4 + 1] = f2bf(v.y);
    out[i * 4 + 2] = f2bf(v.z); out[i * 4 + 3] = f2bf(v.w);
}

// ---------------------------------------------------------------------------
__global__ __launch_bounds__(256) void rmsnorm_bf16(
    const float* __restrict__ x, const float* __restrict__ w,
    short* __restrict__ out, int ncols)
{
    const int row = blockIdx.x;
    const float* xr = x + (size_t)row * ncols;
    float ss = 0.f;
    for (int c = threadIdx.x; c < ncols; c += 256) { float v = xr[c]; ss += v * v; }
    #pragma unroll
    for (int off = 32; off > 0; off >>= 1) ss += __shfl_down(ss, off, 64);
    __shared__ float red[4];
    __shared__ float stot;
    if ((threadIdx.x & 63) == 0) red[threadIdx.x >> 6] = ss;
    __syncthreads();
    if (threadIdx.x == 0) stot = red[0] + red[1] + red[2] + red[3];
    __syncthreads();
    const float scale = rsqrtf(stot / (float)ncols + EPS_);
    for (int c = threadIdx.x; c < ncols; c += 256)
        out[(size_t)row * ncols + c] = f2bf(xr[c] * scale * w[c]);
}

__global__ __launch_bounds__(256) void rmsnorm_f32(
    const float* __restrict__ x, const float* __restrict__ w,
    float* __restrict__ out, int ncols)
{
    const int row = blockIdx.x;
    const float* xr = x + (size_t)row * ncols;
    float ss = 0.f;
    for (int c = threadIdx.x; c < ncols; c += 256) { float v = xr[c]; ss += v * v; }
    #pragma unroll
    for (int off = 32; off > 0; off >>= 1) ss += __shfl_down(ss, off, 64);
    __shared__ float red[4];
    __shared__ float stot;
    if ((threadIdx.x & 63) == 0) red[threadIdx.x >> 6] = ss;
    __syncthreads();
    if (threadIdx.x == 0) stot = red[0] + red[1] + red[2] + red[3];
    __syncthreads();
    const float scale = rsqrtf(stot / (float)ncols + EPS_);
    for (int c = threadIdx.x; c < ncols; c += 256)
        out[(size_t)row * ncols + c] = xr[c] * scale * w[c];
}

// ---------------------------------------------------------------------------
__global__ __launch_bounds__(256) void conv_silu_kernel(
    const float* __restrict__ xz, const float* __restrict__ cw,
    const float* __restrict__ cb, float* __restrict__ xc,
    short* __restrict__ xcb16)
{
    int idx = blockIdx.x * 256 + threadIdx.x;
    if (idx >= MROWS * I_) return;
    int i  = idx % I_;
    int bs = idx / I_;
    int s  = bs % S_;
    int b  = bs / S_;
    const float* base = xz + (size_t)b * S_ * (2 * I_) + i;
    float acc = cb[i];
    #pragma unroll
    for (int k = 0; k < K_; ++k) {
        int ss = s - (K_ - 1) + k;
        if (ss >= 0) acc = fmaf(cw[i * K_ + k], base[(size_t)ss * (2 * I_)], acc);
    }
    float v = siluf(acc);
    xc[idx] = v;
    xcb16[idx] = f2bf(v);
}

// ---------------------------------------------------------------------------
// Chunk-parallel selective scan (3 passes).
// ---------------------------------------------------------------------------
__global__ __launch_bounds__(256) void scan_pass1(
    const float* __restrict__ xc, const float* __restrict__ dt,
    const float* __restrict__ dbc, const float* __restrict__ A_log,
    float* __restrict__ P, float* __restrict__ hend)
{
    const int g   = threadIdx.x >> 4;
    const int n   = threadIdx.x & 15;
    const int gid = blockIdx.x * 16 + g;
    const int i   = gid % I_;
    const int c   = (gid / I_) % C_;
    const int b   = gid / (I_ * C_);
    const float a = -expf(A_log[i * N_ + n]);
    const int s0  = c * T_;
    const float* dtp = dt  + ((size_t)b * S_ + s0) * I_ + i;
    const float* xcp = xc  + ((size_t)b * S_ + s0) * I_ + i;
    const float* dbp = dbc + ((size_t)b * S_ + s0) * 80 + R_ + n;
    float p = 1.f, h = 0.f;
    #pragma unroll 4
    for (int s = 0; s < T_; ++s) {
        float dtv = dtp[(size_t)s * I_];
        float xcv = xcp[(size_t)s * I_];
        float Bv  = dbp[s * 80];
        float dA  = expf(dtv * a);
        h = fmaf(dA, h, dtv * xcv * Bv);
        p *= dA;
    }
    size_t o = ((size_t)gid) * N_ + n;
    P[o] = p; hend[o] = h;
}

__global__ __launch_bounds__(256) void scan_pass2(
    const float* __restrict__ P, const float* __restrict__ hend,
    float* __restrict__ Hstart)
{
    int idx = blockIdx.x * 256 + threadIdx.x;
    if (idx >= B_ * I_ * N_) return;
    int n = idx & 15;
    int i = (idx >> 4) % I_;
    int b = idx / (I_ * N_);
    float H = 0.f;
    #pragma unroll
    for (int c = 0; c < C_; ++c) {
        size_t o = (((size_t)b * C_ + c) * I_ + i) * (size_t)N_ + n;
        Hstart[o] = H;
        H = fmaf(P[o], H, hend[o]);
    }
}

__global__ __launch_bounds__(256) void scan_pass3(
    const float* __restrict__ xc, const float* __restrict__ dt,
    const float* __restrict__ dbc, const float* __restrict__ xz,
    const float* __restrict__ A_log, const float* __restrict__ D,
    const float* __restrict__ Hstart, short* __restrict__ y16)
{
    const int g   = threadIdx.x >> 4;
    const int n   = threadIdx.x & 15;
    const int gid = blockIdx.x * 16 + g;
    const int i   = gid % I_;
    const int c   = (gid / I_) % C_;
    const int b   = gid / (I_ * C_);
    const float a  = -expf(A_log[i * N_ + n]);
    const float Dv = D[i];
    const int s0   = c * T_;
    const float* dtp = dt  + ((size_t)b * S_ + s0) * I_ + i;
    const float* xcp = xc  + ((size_t)b * S_ + s0) * I_ + i;
    const float* dbp = dbc + ((size_t)b * S_ + s0) * 80;
    const float* zp  = xz  + ((size_t)b * S_ + s0) * (2 * I_) + I_ + i;
    short*       yp  = y16 + ((size_t)b * S_ + s0) * I_ + i;
    float h = Hstart[((size_t)gid) * N_ + n];
    for (int s = 0; s < T_; ++s) {
        float dtv = dtp[(size_t)s * I_];
        float xcv = xcp[(size_t)s * I_];
        float Bv  = dbp[s * 80 + R_ + n];
        float Cv  = dbp[s * 80 + R_ + N_ + n];
        float dA  = expf(dtv * a);
        h = fmaf(dA, h, dtv * xcv * Bv);
        float yv = h * Cv;
        #pragma unroll
        for (int off = 8; off > 0; off >>= 1) yv += __shfl_xor(yv, off, 16);
        if (n == 0) {
            float zv = zp[(size_t)s * (2 * I_)];
            yp[(size_t)s * I_] = f2bf((yv + xcv * Dv) * siluf(zv));
        }
    }
}

// ---------------------------------------------------------------------------
extern "C" void kernel_launch(void* const* d_in, const int* in_sizes, int n_in,
                              void* d_out, int out_size, void* d_ws, size_t ws_size,
                              hipStream_t stream)
{
    const float* x     = (const float*)d_in[0];
    const float* W_in  = (const float*)d_in[1];
    const float* b_in  = (const float*)d_in[2];
    const float* norm_w= (const float*)d_in[3];
    const float* ipw   = (const float*)d_in[4];
    const float* cw    = (const float*)d_in[5];
    const float* cb    = (const float*)d_in[6];
    const float* xpw   = (const float*)d_in[7];
    const float* dpw   = (const float*)d_in[8];
    const float* dpb   = (const float*)d_in[9];
    const float* A_log = (const float*)d_in[10];
    const float* Dp    = (const float*)d_in[11];
    const float* opw   = (const float*)d_in[12];
    const float* nfw   = (const float*)d_in[13];
    float* out = (float*)d_out;

    // fp32 scratch
    float* wsf  = (float*)d_ws;
    float* h    = wsf;  wsf += (size_t)MROWS * H_;
    float* xzb  = wsf;  wsf += (size_t)MROWS * 2 * I_;
    float* xcb  = wsf;  wsf += (size_t)MROWS * I_;
    float* dbcb = wsf;  wsf += (size_t)MROWS * 80;
    float* dtb  = wsf;  wsf += (size_t)MROWS * I_;
    float* Pb   = wsf;  wsf += (size_t)B_ * C_ * I_ * N_;
    float* heb  = wsf;  wsf += (size_t)B_ * C_ * I_ * N_;
    float* Hsb  = wsf;  wsf += (size_t)B_ * C_ * I_ * N_;
    // bf16 scratch
    short* wss   = (short*)wsf;
    short* x_bf  = wss;  wss += (size_t)MROWS * CIN_;
    short* u_bf  = wss;  wss += (size_t)MROWS * H_;
    short* xc_bf = wss;  wss += (size_t)MROWS * I_;
    short* y_bf  = wss;  wss += (size_t)MROWS * I_;
    short* WinT  = wss;  wss += (size_t)H_ * CIN_;
    short* ipwT  = wss;  wss += (size_t)L_ * 2 * I_ * H_;
    short* xpwT  = wss;  wss += (size_t)L_ * 128 * I_;
    short* opwT  = wss;  wss += (size_t)L_ * H_ * I_;

    // split-K partial buffers alias dead scratch (sizes checked):
    // part_Win: 2*2048*768 floats == dtb (2048*1536) exactly
    // part_x  : 8*2048*80  floats (5.2MB) <= dtb (12.6MB)
    // part_o  : 3*2048*768 floats (18.9MB) <= xzb (24.1MB)
    float* part_Win = dtb;
    float* part_x   = dtb;
    float* part_o   = xzb;

    const dim3 blk(256);
    const dim3 tblk(32, 8);

    // one-time conversions
    cast_bf16<<<(MROWS * CIN_ / 4 + 255) / 256, blk, 0, stream>>>(x, x_bf, MROWS * CIN_ / 4);
    wtrans<<<dim3(H_ / 32, CIN_ / 32), tblk, 0, stream>>>(W_in, WinT, CIN_, H_, CIN_, H_);
    for (int l = 0; l < L_; ++l) {
        wtrans<<<dim3(2 * I_ / 32, H_ / 32), tblk, 0, stream>>>(
            ipw + (size_t)l * H_ * 2 * I_, ipwT + (size_t)l * 2 * I_ * H_, H_, 2 * I_, H_, 2 * I_);
        wtrans<<<dim3(128 / 32, I_ / 32), tblk, 0, stream>>>(
            xpw + (size_t)l * I_ * 80, xpwT + (size_t)l * 128 * I_, I_, 80, I_, 128);
        wtrans<<<dim3(H_ / 32, I_ / 32), tblk, 0, stream>>>(
            opw + (size_t)l * I_ * H_, opwT + (size_t)l * H_ * I_, I_, H_, I_, H_);
    }

    // h = x @ W_in + b_in   (split-K=2)
    gemm_mfma<<<dim3(H_ / 128, MROWS / 128, 2), blk, 0, stream>>>(
        x_bf, WinT, nullptr, part_Win, MROWS, H_, CIN_, CIN_, CIN_, H_, 0);
    reduce_parts<<<(MROWS * H_ + 255) / 256, blk, 0, stream>>>(
        part_Win, h, b_in, MROWS * H_, H_, 2, 1);

    for (int l = 0; l < L_; ++l) {
        rmsnorm_bf16<<<MROWS, blk, 0, stream>>>(h, norm_w + l * H_, u_bf, H_);
        // xz = u @ in_proj_w
        gemm_mfma<<<dim3(2 * I_ / 128, MROWS / 128, 1), blk, 0, stream>>>(
            u_bf, ipwT + (size_t)l * 2 * I_ * H_, nullptr, xzb,
            MROWS, 2 * I_, H_, H_, H_, 2 * I_, 0);
        conv_silu_kernel<<<(MROWS * I_ + 255) / 256, blk, 0, stream>>>(
            xzb, cw + l * I_ * K_, cb + l * I_, xcb, xc_bf);
        // dbc = xc @ x_proj_w   (split-K=8, N=80 in one 128 tile)
        gemm_mfma<<<dim3(1, MROWS / 128, 8), blk, 0, stream>>>(
            xc_bf, xpwT + (size_t)l * 128 * I_, nullptr, part_x,
            MROWS, 80, I_, I_, I_, 80, 0);
        reduce_parts<<<(MROWS * 80 + 255) / 256, blk, 0, stream>>>(
            part_x, dbcb, nullptr, MROWS * 80, 80, 8, 0);
        // dt = softplus(dbc[:, :48] @ dt_proj_w + b)  (fp32 VALU kernel)
        dt_kernel<<<dim3(I_ / 64, MROWS / 64), blk, 0, stream>>>(
            dbcb, dpw + (size_t)l * R_ * I_, dpb + l * I_, dtb);
        // chunked selective scan
        scan_pass1<<<(B_ * C_ * I_ * 16) / 256, blk, 0, stream>>>(
            xcb, dtb, dbcb, A_log + l * I_ * N_, Pb, heb);
        scan_pass2<<<(B_ * I_ * N_ + 255) / 256, blk, 0, stream>>>(Pb, heb, Hsb);
        scan_pass3<<<(B_ * C_ * I_ * 16) / 256, blk, 0, stream>>>(
            xcb, dtb, dbcb, xzb, A_log + l * I_ * N_, Dp + l * I_, Hsb, y_bf);
        // h += y @ out_proj_w   (split-K=3; partials alias xzb, now dead)
        gemm_mfma<<<dim3(H_ / 128, MROWS / 128, 3), blk, 0, stream>>>(
            y_bf, opwT + (size_t)l * H_ * I_, nullptr, part_o,
            MROWS, H_, I_, I_, I_, H_, 0);
        reduce_parts<<<(MROWS * H_ + 255) / 256, blk, 0, stream>>>(
            part_o, h, nullptr, MROWS * H_, H_, 3, 2);
    }

    rmsnorm_f32<<<MROWS, blk, 0, stream>>>(h, nfw, out, H_);
}

// Round 6
// 1075.468 us; speedup vs baseline: 4.5113x; 1.1081x over previous
//
#include <hip/hip_runtime.h>
#include <cmath>

#define B_    4
#define S_    512
#define CIN_  512
#define H_    768
#define I_    1536
#define N_    16
#define R_    48
#define K_    4
#define L_    4
#define EPS_  1e-5f
#define MROWS (B_ * S_)   // 2048
#define C_    16          // scan chunks
#define T_    (S_ / C_)   // 32 steps per chunk

typedef __attribute__((ext_vector_type(8))) short bf16x8;
typedef __attribute__((ext_vector_type(4))) float f32x4;

__device__ __forceinline__ float siluf(float x) { return x / (1.f + expf(-x)); }
__device__ __forceinline__ float softplusf(float x) { return x > 20.f ? x : log1pf(expf(x)); }
__device__ __forceinline__ short f2bf(float f) {
    union { float f; unsigned u; } v; v.f = f;
    unsigned r = v.u + 0x7fff + ((v.u >> 16) & 1);
    return (short)(r >> 16);
}

#define GLOAD16(g, l) __builtin_amdgcn_global_load_lds( \
    (const __attribute__((address_space(1))) void*)(g), \
    (__attribute__((address_space(3))) void*)(l), 16, 0, 0)

// ---------------------------------------------------------------------------
// bf16 MFMA GEMM: C[M,N] = A[M,K] @ Bt[N,K]^T  (128x128 tile, BK=32, 4 waves)
// gridDim.z > 1: split-K partials to C + z*M*ldc.  z==1: ep epilogues.
// ---------------------------------------------------------------------------
__global__ __launch_bounds__(256) void gemm_mfma(
    const short* __restrict__ A, const short* __restrict__ Bt,
    const float* __restrict__ bias, float* __restrict__ C,
    int M, int N, int Kd, int lda, int ldb, int ldc, int ep)
{
    __shared__ __align__(16) short Asl[128 * 32];
    __shared__ __align__(16) short Bsl[128 * 32];
    const int tid = threadIdx.x;
    const int ln  = tid & 63;
    const int wv  = tid >> 6;
    const int wm  = wv >> 1, wn = wv & 1;
    const int row0 = blockIdx.y * 128;
    const int col0 = blockIdx.x * 128;
    const int nz   = gridDim.z;
    const int kchunk = Kd / nz;
    const int kbeg   = blockIdx.z * kchunk;

    f32x4 acc[4][4];
    #pragma unroll
    for (int i = 0; i < 4; ++i)
        #pragma unroll
        for (int j = 0; j < 4; ++j) acc[i][j] = (f32x4){0.f, 0.f, 0.f, 0.f};

    const int c0 = tid, c1 = tid + 256;
    const short* ga0 = A  + (size_t)(row0 + (c0 >> 2)) * lda + (c0 & 3) * 8;
    const short* ga1 = A  + (size_t)(row0 + (c1 >> 2)) * lda + (c1 & 3) * 8;
    const short* gb0 = Bt + (size_t)(col0 + (c0 >> 2)) * ldb + (c0 & 3) * 8;
    const short* gb1 = Bt + (size_t)(col0 + (c1 >> 2)) * ldb + (c1 & 3) * 8;
    short* la0 = &Asl[(wv * 64) * 8];
    short* la1 = &Asl[(256 + wv * 64) * 8];
    short* lb0 = &Bsl[(wv * 64) * 8];
    short* lb1 = &Bsl[(256 + wv * 64) * 8];

    const int lrow = ln & 15;
    const int lk   = (ln >> 4) * 8;

    for (int k0 = kbeg; k0 < kbeg + kchunk; k0 += 32) {
        GLOAD16(ga0 + k0, la0);
        GLOAD16(ga1 + k0, la1);
        GLOAD16(gb0 + k0, lb0);
        GLOAD16(gb1 + k0, lb1);
        __syncthreads();
        bf16x8 af[4], bfr[4];
        #pragma unroll
        for (int fm = 0; fm < 4; ++fm)
            af[fm] = *(const bf16x8*)&Asl[(wm * 64 + fm * 16 + lrow) * 32 + lk];
        #pragma unroll
        for (int fn = 0; fn < 4; ++fn)
            bfr[fn] = *(const bf16x8*)&Bsl[(wn * 64 + fn * 16 + lrow) * 32 + lk];
        #pragma unroll
        for (int fm = 0; fm < 4; ++fm)
            #pragma unroll
            for (int fn = 0; fn < 4; ++fn)
                acc[fm][fn] = __builtin_amdgcn_mfma_f32_16x16x32_bf16(
                    af[fm], bfr[fn], acc[fm][fn], 0, 0, 0);
        __syncthreads();
    }

    const int erow = (ln >> 4) * 4;
    const int ecol = ln & 15;
    const size_t zoff = (size_t)blockIdx.z * M * ldc;
    #pragma unroll
    for (int fm = 0; fm < 4; ++fm) {
        #pragma unroll
        for (int fn = 0; fn < 4; ++fn) {
            int gn = col0 + wn * 64 + fn * 16 + ecol;
            if (gn >= N) continue;
            #pragma unroll
            for (int r = 0; r < 4; ++r) {
                int gm = row0 + wm * 64 + fm * 16 + erow + r;
                float v = acc[fm][fn][r];
                size_t o = (size_t)gm * ldc + gn;
                if (nz > 1) { C[zoff + o] = v; continue; }
                if (ep == 1)      v += bias[gn];
                else if (ep == 2) v  = softplusf(v + bias[gn]);
                else if (ep == 3) v += C[o];
                C[o] = v;
            }
        }
    }
}

// ---------------------------------------------------------------------------
__global__ __launch_bounds__(256) void reduce_parts(
    const float* __restrict__ part, float* __restrict__ C,
    const float* __restrict__ bias, int total, int ldc, int nz, int mode)
{
    int idx = blockIdx.x * 256 + threadIdx.x;
    if (idx >= total) return;
    size_t strideZ = (size_t)total;
    float s = 0.f;
    for (int z = 0; z < nz; ++z) s += part[idx + z * strideZ];
    if (mode == 1)      s += bias[idx % ldc];
    else if (mode == 2) s += C[idx];
    C[idx] = s;
}

// ---------------------------------------------------------------------------
// dt_proj fused: dt[m][n] = softplus(dbc[m][:48] @ dpw[:,n] + dpb[n]), fp32.
// ---------------------------------------------------------------------------
__global__ __launch_bounds__(256) void dt_kernel(
    const float* __restrict__ dbc, const float* __restrict__ dpw,
    const float* __restrict__ dpb, float* __restrict__ dt)
{
    __shared__ float As[64][49];
    __shared__ float Bs[48][65];
    const int tid  = threadIdx.x;
    const int row0 = blockIdx.y * 64;
    const int col0 = blockIdx.x * 64;
    for (int idx = tid; idx < 64 * 48; idx += 256) {
        int m = idx / 48, k = idx - m * 48;
        As[m][k] = dbc[(size_t)(row0 + m) * 80 + k];
    }
    for (int idx = tid; idx < 48 * 64; idx += 256) {
        int k = idx >> 6, n = idx & 63;
        Bs[k][n] = dpw[(size_t)k * I_ + col0 + n];
    }
    __syncthreads();
    const int tx = tid & 15, ty = tid >> 4;
    float acc[4][4] = {};
    #pragma unroll
    for (int k = 0; k < 48; ++k) {
        float a[4], b[4];
        #pragma unroll
        for (int i = 0; i < 4; ++i) a[i] = As[ty * 4 + i][k];
        #pragma unroll
        for (int j = 0; j < 4; ++j) b[j] = Bs[k][tx * 4 + j];
        #pragma unroll
        for (int i = 0; i < 4; ++i)
            #pragma unroll
            for (int j = 0; j < 4; ++j)
                acc[i][j] = fmaf(a[i], b[j], acc[i][j]);
    }
    #pragma unroll
    for (int i = 0; i < 4; ++i) {
        int gm = row0 + ty * 4 + i;
        #pragma unroll
        for (int j = 0; j < 4; ++j) {
            int gn = col0 + tx * 4 + j;
            dt[(size_t)gm * I_ + gn] = softplusf(acc[i][j] + dpb[gn]);
        }
    }
}

// ---------------------------------------------------------------------------
__global__ __launch_bounds__(256) void wtrans(
    const float* __restrict__ in, short* __restrict__ out,
    int Kd, int Nn, int Kpad, int Npad)
{
    __shared__ float t[32][33];
    const int n0 = blockIdx.x * 32, k0 = blockIdx.y * 32;
    const int tx = threadIdx.x, ty = threadIdx.y;
    #pragma unroll
    for (int j = 0; j < 32; j += 8) {
        int k = k0 + ty + j, n = n0 + tx;
        t[ty + j][tx] = (k < Kd && n < Nn) ? in[(size_t)k * Nn + n] : 0.f;
    }
    __syncthreads();
    #pragma unroll
    for (int j = 0; j < 32; j += 8) {
        int np = n0 + ty + j, kp = k0 + tx;
        if (np < Npad && kp < Kpad) out[(size_t)np * Kpad + kp] = f2bf(t[tx][ty + j]);
    }
}

__global__ __launch_bounds__(256) void cast_bf16(
    const float* __restrict__ in, short* __restrict__ out, int n4)
{
    int i = blockIdx.x * 256 + threadIdx.x;
    if (i >= n4) return;
    float4 v = ((const float4*)in)[i];
    out[i * 4 + 0] = f2bf(v.x); out[i * 4 + 1] = f2bf(v.y);
    out[i * 4 + 2] = f2bf(v.z); out[i * 4 + 3] = f2bf(v.w);
}

// ---------------------------------------------------------------------------
__global__ __launch_bounds__(256) void rmsnorm_bf16(
    const float* __restrict__ x, const float* __restrict__ w,
    short* __restrict__ out, int ncols)
{
    const int row = blockIdx.x;
    const float* xr = x + (size_t)row * ncols;
    float ss = 0.f;
    for (int c = threadIdx.x; c < ncols; c += 256) { float v = xr[c]; ss += v * v; }
    #pragma unroll
    for (int off = 32; off > 0; off >>= 1) ss += __shfl_down(ss, off, 64);
    __shared__ float red[4];
    __shared__ float stot;
    if ((threadIdx.x & 63) == 0) red[threadIdx.x >> 6] = ss;
    __syncthreads();
    if (threadIdx.x == 0) stot = red[0] + red[1] + red[2] + red[3];
    __syncthreads();
    const float scale = rsqrtf(stot / (float)ncols + EPS_);
    for (int c = threadIdx.x; c < ncols; c += 256)
        out[(size_t)row * ncols + c] = f2bf(xr[c] * scale * w[c]);
}

__global__ __launch_bounds__(256) void rmsnorm_f32(
    const float* __restrict__ x, const float* __restrict__ w,
    float* __restrict__ out, int ncols)
{
    const int row = blockIdx.x;
    const float* xr = x + (size_t)row * ncols;
    float ss = 0.f;
    for (int c = threadIdx.x; c < ncols; c += 256) { float v = xr[c]; ss += v * v; }
    #pragma unroll
    for (int off = 32; off > 0; off >>= 1) ss += __shfl_down(ss, off, 64);
    __shared__ float red[4];
    __shared__ float stot;
    if ((threadIdx.x & 63) == 0) red[threadIdx.x >> 6] = ss;
    __syncthreads();
    if (threadIdx.x == 0) stot = red[0] + red[1] + red[2] + red[3];
    __syncthreads();
    const float scale = rsqrtf(stot / (float)ncols + EPS_);
    for (int c = threadIdx.x; c < ncols; c += 256)
        out[(size_t)row * ncols + c] = xr[c] * scale * w[c];
}

// ---------------------------------------------------------------------------
__global__ __launch_bounds__(256) void conv_silu_kernel(
    const float* __restrict__ xz, const float* __restrict__ cw,
    const float* __restrict__ cb, float* __restrict__ xc,
    short* __restrict__ xcb16)
{
    int idx = blockIdx.x * 256 + threadIdx.x;
    if (idx >= MROWS * I_) return;
    int i  = idx % I_;
    int bs = idx / I_;
    int s  = bs % S_;
    int b  = bs / S_;
    const float* base = xz + (size_t)b * S_ * (2 * I_) + i;
    float acc = cb[i];
    #pragma unroll
    for (int k = 0; k < K_; ++k) {
        int ss = s - (K_ - 1) + k;
        if (ss >= 0) acc = fmaf(cw[i * K_ + k], base[(size_t)ss * (2 * I_)], acc);
    }
    float v = siluf(acc);
    xc[idx] = v;
    xcb16[idx] = f2bf(v);
}

// ---------------------------------------------------------------------------
// Chunk-parallel selective scan, 4 lanes/channel, 4 states/lane in registers.
// Block = 256 threads = 64 channels, one (b, chunk). B/C staged in LDS.
// P/hend/Hstart layout: [B][C][I][N].
// ---------------------------------------------------------------------------
__global__ __launch_bounds__(256) void scan_pass1(
    const float* __restrict__ xc, const float* __restrict__ dt,
    const float* __restrict__ dbc, const float* __restrict__ A_log,
    float* __restrict__ P, float* __restrict__ hend)
{
    __shared__ float Bsh[T_][16];
    const int tid = threadIdx.x;
    const int lc  = tid >> 2;          // channel within block
    const int sub = tid & 3;           // owns states sub*4 .. sub*4+3
    const int ib  = blockIdx.x % (I_ / 64);
    const int c   = (blockIdx.x / (I_ / 64)) % C_;
    const int b   = blockIdx.x / ((I_ / 64) * C_);
    const int i   = ib * 64 + lc;
    const int s0  = c * T_;

    // stage B (T_ x 16 floats)
    for (int idx = tid; idx < T_ * 4; idx += 256) {
        int row = idx >> 2, q = idx & 3;
        *(float4*)&Bsh[row][q * 4] =
            *(const float4*)&dbc[((size_t)b * S_ + s0 + row) * 80 + R_ + q * 4];
    }

    float a[4], h[4] = {0.f, 0.f, 0.f, 0.f}, p[4] = {1.f, 1.f, 1.f, 1.f};
    #pragma unroll
    for (int j = 0; j < 4; ++j) a[j] = -expf(A_log[i * N_ + sub * 4 + j]);

    const float* dtp = dt + ((size_t)b * S_ + s0) * I_ + i;
    const float* xcp = xc + ((size_t)b * S_ + s0) * I_ + i;
    __syncthreads();

    float dtv = dtp[0], xcv = xcp[0];
    for (int s = 0; s < T_; ++s) {
        float dtn = 0.f, xcn = 0.f;
        if (s + 1 < T_) { dtn = dtp[(size_t)(s + 1) * I_]; xcn = xcp[(size_t)(s + 1) * I_]; }
        float4 Bv = *(const float4*)&Bsh[s][sub * 4];
        float dx = dtv * xcv;
        #pragma unroll
        for (int j = 0; j < 4; ++j) {
            float dA = expf(dtv * a[j]);
            float Bj = (j == 0) ? Bv.x : (j == 1) ? Bv.y : (j == 2) ? Bv.z : Bv.w;
            h[j] = fmaf(dA, h[j], dx * Bj);
            p[j] *= dA;
        }
        dtv = dtn; xcv = xcn;
    }
    size_t o = (((size_t)b * C_ + c) * I_ + i) * N_ + sub * 4;
    *(float4*)&P[o]    = (float4){p[0], p[1], p[2], p[3]};
    *(float4*)&hend[o] = (float4){h[0], h[1], h[2], h[3]};
}

__global__ __launch_bounds__(256) void scan_pass2(
    const float* __restrict__ P, const float* __restrict__ hend,
    float* __restrict__ Hstart)
{
    int idx = blockIdx.x * 256 + threadIdx.x;   // over B*I*N
    if (idx >= B_ * I_ * N_) return;
    int n = idx & 15;
    int i = (idx >> 4) % I_;
    int b = idx / (I_ * N_);
    float H = 0.f;
    #pragma unroll
    for (int c = 0; c < C_; ++c) {
        size_t o = (((size_t)b * C_ + c) * I_ + i) * (size_t)N_ + n;
        Hstart[o] = H;
        H = fmaf(P[o], H, hend[o]);
    }
}

__global__ __launch_bounds__(256) void scan_pass3(
    const float* __restrict__ xc, const float* __restrict__ dt,
    const float* __restrict__ dbc, const float* __restrict__ xz,
    const float* __restrict__ A_log, const float* __restrict__ D,
    const float* __restrict__ Hstart, short* __restrict__ y16)
{
    __shared__ float Bsh[T_][16];
    __shared__ float Csh[T_][16];
    const int tid = threadIdx.x;
    const int lc  = tid >> 2;
    const int sub = tid & 3;
    const int ib  = blockIdx.x % (I_ / 64);
    const int c   = (blockIdx.x / (I_ / 64)) % C_;
    const int b   = blockIdx.x / ((I_ / 64) * C_);
    const int i   = ib * 64 + lc;
    const int s0  = c * T_;

    for (int idx = tid; idx < T_ * 4; idx += 256) {
        int row = idx >> 2, q = idx & 3;
        const float* src = &dbc[((size_t)b * S_ + s0 + row) * 80 + R_];
        *(float4*)&Bsh[row][q * 4] = *(const float4*)&src[q * 4];
        *(float4*)&Csh[row][q * 4] = *(const float4*)&src[16 + q * 4];
    }

    float a[4], h[4];
    #pragma unroll
    for (int j = 0; j < 4; ++j) a[j] = -expf(A_log[i * N_ + sub * 4 + j]);
    const float Dv = D[i];

    size_t ho = (((size_t)b * C_ + c) * I_ + i) * N_ + sub * 4;
    float4 h0 = *(const float4*)&Hstart[ho];
    h[0] = h0.x; h[1] = h0.y; h[2] = h0.z; h[3] = h0.w;

    const float* dtp = dt  + ((size_t)b * S_ + s0) * I_ + i;
    const float* xcp = xc  + ((size_t)b * S_ + s0) * I_ + i;
    const float* zp  = xz  + ((size_t)b * S_ + s0) * (2 * I_) + I_ + i;
    short*       yp  = y16 + ((size_t)b * S_ + s0) * I_ + i;
    __syncthreads();

    float dtv = dtp[0], xcv = xcp[0];
    for (int s = 0; s < T_; ++s) {
        float dtn = 0.f, xcn = 0.f;
        if (s + 1 < T_) { dtn = dtp[(size_t)(s + 1) * I_]; xcn = xcp[(size_t)(s + 1) * I_]; }
        float4 Bv = *(const float4*)&Bsh[s][sub * 4];
        float4 Cv = *(const float4*)&Csh[s][sub * 4];
        float dx = dtv * xcv;
        float yv;
        {
            float dA0 = expf(dtv * a[0]);
            float dA1 = expf(dtv * a[1]);
            float dA2 = expf(dtv * a[2]);
            float dA3 = expf(dtv * a[3]);
            h[0] = fmaf(dA0, h[0], dx * Bv.x);
            h[1] = fmaf(dA1, h[1], dx * Bv.y);
            h[2] = fmaf(dA2, h[2], dx * Bv.z);
            h[3] = fmaf(dA3, h[3], dx * Bv.w);
            yv = h[0] * Cv.x;
            yv = fmaf(h[1], Cv.y, yv);
            yv = fmaf(h[2], Cv.z, yv);
            yv = fmaf(h[3], Cv.w, yv);
        }
        yv += __shfl_xor(yv, 1, 4);
        yv += __shfl_xor(yv, 2, 4);
        if (sub == 0) {
            float zv = zp[(size_t)s * (2 * I_)];
            yp[(size_t)s * I_] = f2bf((yv + xcv * Dv) * siluf(zv));
        }
        dtv = dtn; xcv = xcn;
    }
}

// ---------------------------------------------------------------------------
extern "C" void kernel_launch(void* const* d_in, const int* in_sizes, int n_in,
                              void* d_out, int out_size, void* d_ws, size_t ws_size,
                              hipStream_t stream)
{
    const float* x     = (const float*)d_in[0];
    const float* W_in  = (const float*)d_in[1];
    const float* b_in  = (const float*)d_in[2];
    const float* norm_w= (const float*)d_in[3];
    const float* ipw   = (const float*)d_in[4];
    const float* cw    = (const float*)d_in[5];
    const float* cb    = (const float*)d_in[6];
    const float* xpw   = (const float*)d_in[7];
    const float* dpw   = (const float*)d_in[8];
    const float* dpb   = (const float*)d_in[9];
    const float* A_log = (const float*)d_in[10];
    const float* Dp    = (const float*)d_in[11];
    const float* opw   = (const float*)d_in[12];
    const float* nfw   = (const float*)d_in[13];
    float* out = (float*)d_out;

    // fp32 scratch
    float* wsf  = (float*)d_ws;
    float* h    = wsf;  wsf += (size_t)MROWS * H_;
    float* xzb  = wsf;  wsf += (size_t)MROWS * 2 * I_;
    float* xcb  = wsf;  wsf += (size_t)MROWS * I_;
    float* dbcb = wsf;  wsf += (size_t)MROWS * 80;
    float* dtb  = wsf;  wsf += (size_t)MROWS * I_;
    float* Pb   = wsf;  wsf += (size_t)B_ * C_ * I_ * N_;
    float* heb  = wsf;  wsf += (size_t)B_ * C_ * I_ * N_;
    float* Hsb  = wsf;  wsf += (size_t)B_ * C_ * I_ * N_;
    // bf16 scratch
    short* wss   = (short*)wsf;
    short* x_bf  = wss;  wss += (size_t)MROWS * CIN_;
    short* u_bf  = wss;  wss += (size_t)MROWS * H_;
    short* xc_bf = wss;  wss += (size_t)MROWS * I_;
    short* y_bf  = wss;  wss += (size_t)MROWS * I_;
    short* WinT  = wss;  wss += (size_t)H_ * CIN_;
    short* ipwT  = wss;  wss += (size_t)L_ * 2 * I_ * H_;
    short* xpwT  = wss;  wss += (size_t)L_ * 128 * I_;
    short* opwT  = wss;  wss += (size_t)L_ * H_ * I_;

    // split-K partial aliases (dead at use time):
    float* part_Win = dtb;   // 2*2048*768  <= 2048*1536
    float* part_x   = dtb;   // 8*2048*80   <= 2048*1536
    float* part_o   = xzb;   // 3*2048*768  <= 2048*3072

    const dim3 blk(256);
    const dim3 tblk(32, 8);

    // one-time conversions
    cast_bf16<<<(MROWS * CIN_ / 4 + 255) / 256, blk, 0, stream>>>(x, x_bf, MROWS * CIN_ / 4);
    wtrans<<<dim3(H_ / 32, CIN_ / 32), tblk, 0, stream>>>(W_in, WinT, CIN_, H_, CIN_, H_);
    for (int l = 0; l < L_; ++l) {
        wtrans<<<dim3(2 * I_ / 32, H_ / 32), tblk, 0, stream>>>(
            ipw + (size_t)l * H_ * 2 * I_, ipwT + (size_t)l * 2 * I_ * H_, H_, 2 * I_, H_, 2 * I_);
        wtrans<<<dim3(128 / 32, I_ / 32), tblk, 0, stream>>>(
            xpw + (size_t)l * I_ * 80, xpwT + (size_t)l * 128 * I_, I_, 80, I_, 128);
        wtrans<<<dim3(H_ / 32, I_ / 32), tblk, 0, stream>>>(
            opw + (size_t)l * I_ * H_, opwT + (size_t)l * H_ * I_, I_, H_, I_, H_);
    }

    // h = x @ W_in + b_in   (split-K=2)
    gemm_mfma<<<dim3(H_ / 128, MROWS / 128, 2), blk, 0, stream>>>(
        x_bf, WinT, nullptr, part_Win, MROWS, H_, CIN_, CIN_, CIN_, H_, 0);
    reduce_parts<<<(MROWS * H_ + 255) / 256, blk, 0, stream>>>(
        part_Win, h, b_in, MROWS * H_, H_, 2, 1);

    const int scan_blocks = B_ * C_ * (I_ / 64);   // 1536

    for (int l = 0; l < L_; ++l) {
        rmsnorm_bf16<<<MROWS, blk, 0, stream>>>(h, norm_w + l * H_, u_bf, H_);
        gemm_mfma<<<dim3(2 * I_ / 128, MROWS / 128, 1), blk, 0, stream>>>(
            u_bf, ipwT + (size_t)l * 2 * I_ * H_, nullptr, xzb,
            MROWS, 2 * I_, H_, H_, H_, 2 * I_, 0);
        conv_silu_kernel<<<(MROWS * I_ + 255) / 256, blk, 0, stream>>>(
            xzb, cw + l * I_ * K_, cb + l * I_, xcb, xc_bf);
        gemm_mfma<<<dim3(1, MROWS / 128, 8), blk, 0, stream>>>(
            xc_bf, xpwT + (size_t)l * 128 * I_, nullptr, part_x,
            MROWS, 80, I_, I_, I_, 80, 0);
        reduce_parts<<<(MROWS * 80 + 255) / 256, blk, 0, stream>>>(
            part_x, dbcb, nullptr, MROWS * 80, 80, 8, 0);
        dt_kernel<<<dim3(I_ / 64, MROWS / 64), blk, 0, stream>>>(
            dbcb, dpw + (size_t)l * R_ * I_, dpb + l * I_, dtb);
        // chunked selective scan (register-state)
        scan_pass1<<<scan_blocks, blk, 0, stream>>>(
            xcb, dtb, dbcb, A_log + l * I_ * N_, Pb, heb);
        scan_pass2<<<(B_ * I_ * N_ + 255) / 256, blk, 0, stream>>>(Pb, heb, Hsb);
        scan_pass3<<<scan_blocks, blk, 0, stream>>>(
            xcb, dtb, dbcb, xzb, A_log + l * I_ * N_, Dp + l * I_, Hsb, y_bf);
        gemm_mfma<<<dim3(H_ / 128, MROWS / 128, 3), blk, 0, stream>>>(
            y_bf, opwT + (size_t)l * H_ * I_, nullptr, part_o,
            MROWS, H_, I_, I_, I_, H_, 0);
        reduce_parts<<<(MROWS * H_ + 255) / 256, blk, 0, stream>>>(
            part_o, h, nullptr, MROWS * H_, H_, 3, 2);
    }

    rmsnorm_f32<<<MROWS, blk, 0, stream>>>(h, nfw, out, H_);
}

// Round 7
// 1062.870 us; speedup vs baseline: 4.5648x; 1.0119x over previous
//
#include <hip/hip_runtime.h>
#include <cmath>

#define B_    4
#define S_    512
#define CIN_  512
#define H_    768
#define I_    1536
#define N_    16
#define R_    48
#define K_    4
#define L_    4
#define EPS_  1e-5f
#define MROWS (B_ * S_)   // 2048
#define C_    16          // scan chunks
#define T_    (S_ / C_)   // 32 steps per chunk

typedef __attribute__((ext_vector_type(8))) short bf16x8;
typedef __attribute__((ext_vector_type(4))) float f32x4;

__device__ __forceinline__ float siluf(float x) { return x / (1.f + expf(-x)); }
__device__ __forceinline__ float softplusf(float x) { return x > 20.f ? x : log1pf(expf(x)); }
__device__ __forceinline__ short f2bf(float f) {
    union { float f; unsigned u; } v; v.f = f;
    unsigned r = v.u + 0x7fff + ((v.u >> 16) & 1);
    return (short)(r >> 16);
}

#define GLOAD16(g, l) __builtin_amdgcn_global_load_lds( \
    (const __attribute__((address_space(1))) void*)(g), \
    (__attribute__((address_space(3))) void*)(l), 16, 0, 0)

// ---------------------------------------------------------------------------
// bf16 MFMA GEMM: C[M,N] = A[M,K] @ Bt[N,K]^T  (128x128 tile, BK=32, 4 waves)
// gridDim.z > 1: split-K partials to C + z*M*ldc.  z==1: ep epilogues.
// ---------------------------------------------------------------------------
__global__ __launch_bounds__(256) void gemm_mfma(
    const short* __restrict__ A, const short* __restrict__ Bt,
    const float* __restrict__ bias, float* __restrict__ C,
    int M, int N, int Kd, int lda, int ldb, int ldc, int ep)
{
    __shared__ __align__(16) short Asl[128 * 32];
    __shared__ __align__(16) short Bsl[128 * 32];
    const int tid = threadIdx.x;
    const int ln  = tid & 63;
    const int wv  = tid >> 6;
    const int wm  = wv >> 1, wn = wv & 1;
    const int row0 = blockIdx.y * 128;
    const int col0 = blockIdx.x * 128;
    const int nz   = gridDim.z;
    const int kchunk = Kd / nz;
    const int kbeg   = blockIdx.z * kchunk;

    f32x4 acc[4][4];
    #pragma unroll
    for (int i = 0; i < 4; ++i)
        #pragma unroll
        for (int j = 0; j < 4; ++j) acc[i][j] = (f32x4){0.f, 0.f, 0.f, 0.f};

    const int c0 = tid, c1 = tid + 256;
    const short* ga0 = A  + (size_t)(row0 + (c0 >> 2)) * lda + (c0 & 3) * 8;
    const short* ga1 = A  + (size_t)(row0 + (c1 >> 2)) * lda + (c1 & 3) * 8;
    const short* gb0 = Bt + (size_t)(col0 + (c0 >> 2)) * ldb + (c0 & 3) * 8;
    const short* gb1 = Bt + (size_t)(col0 + (c1 >> 2)) * ldb + (c1 & 3) * 8;
    short* la0 = &Asl[(wv * 64) * 8];
    short* la1 = &Asl[(256 + wv * 64) * 8];
    short* lb0 = &Bsl[(wv * 64) * 8];
    short* lb1 = &Bsl[(256 + wv * 64) * 8];

    const int lrow = ln & 15;
    const int lk   = (ln >> 4) * 8;

    for (int k0 = kbeg; k0 < kbeg + kchunk; k0 += 32) {
        GLOAD16(ga0 + k0, la0);
        GLOAD16(ga1 + k0, la1);
        GLOAD16(gb0 + k0, lb0);
        GLOAD16(gb1 + k0, lb1);
        __syncthreads();
        bf16x8 af[4], bfr[4];
        #pragma unroll
        for (int fm = 0; fm < 4; ++fm)
            af[fm] = *(const bf16x8*)&Asl[(wm * 64 + fm * 16 + lrow) * 32 + lk];
        #pragma unroll
        for (int fn = 0; fn < 4; ++fn)
            bfr[fn] = *(const bf16x8*)&Bsl[(wn * 64 + fn * 16 + lrow) * 32 + lk];
        #pragma unroll
        for (int fm = 0; fm < 4; ++fm)
            #pragma unroll
            for (int fn = 0; fn < 4; ++fn)
                acc[fm][fn] = __builtin_amdgcn_mfma_f32_16x16x32_bf16(
                    af[fm], bfr[fn], acc[fm][fn], 0, 0, 0);
        __syncthreads();
    }

    const int erow = (ln >> 4) * 4;
    const int ecol = ln & 15;
    const size_t zoff = (size_t)blockIdx.z * M * ldc;
    #pragma unroll
    for (int fm = 0; fm < 4; ++fm) {
        #pragma unroll
        for (int fn = 0; fn < 4; ++fn) {
            int gn = col0 + wn * 64 + fn * 16 + ecol;
            if (gn >= N) continue;
            #pragma unroll
            for (int r = 0; r < 4; ++r) {
                int gm = row0 + wm * 64 + fm * 16 + erow + r;
                float v = acc[fm][fn][r];
                size_t o = (size_t)gm * ldc + gn;
                if (nz > 1) { C[zoff + o] = v; continue; }
                if (ep == 1)      v += bias[gn];
                else if (ep == 2) v  = softplusf(v + bias[gn]);
                else if (ep == 3) v += C[o];
                C[o] = v;
            }
        }
    }
}

// ---------------------------------------------------------------------------
__global__ __launch_bounds__(256) void reduce_parts(
    const float* __restrict__ part, float* __restrict__ C,
    const float* __restrict__ bias, int total, int ldc, int nz, int mode)
{
    int idx = blockIdx.x * 256 + threadIdx.x;
    if (idx >= total) return;
    size_t strideZ = (size_t)total;
    float s = 0.f;
    for (int z = 0; z < nz; ++z) s += part[idx + z * strideZ];
    if (mode == 1)      s += bias[idx % ldc];
    else if (mode == 2) s += C[idx];
    C[idx] = s;
}

// ---------------------------------------------------------------------------
// dt_proj fused: dt[m][n] = softplus(dbc[m][:48] @ dpw[:,n] + dpb[n]), fp32.
// Block = 32 rows x 256 cols; one output column per thread; A-slab in LDS.
// ---------------------------------------------------------------------------
__global__ __launch_bounds__(256) void dt_kernel(
    const float* __restrict__ dbc, const float* __restrict__ dpw,
    const float* __restrict__ dpb, float* __restrict__ dt)
{
    __shared__ float As[32][48];
    const int tid  = threadIdx.x;
    const int row0 = blockIdx.y * 32;
    const int n    = blockIdx.x * 256 + tid;

    for (int idx = tid; idx < 32 * 48; idx += 256) {
        int m = idx / 48, k = idx - m * 48;
        As[m][k] = dbc[(size_t)(row0 + m) * 80 + k];
    }
    __syncthreads();

    float acc[32] = {};
    const float* wp = dpw + n;
    for (int k = 0; k < 48; ++k) {
        float w = wp[(size_t)k * I_];
        #pragma unroll
        for (int m = 0; m < 32; ++m)
            acc[m] = fmaf(As[m][k], w, acc[m]);
    }
    const float bv = dpb[n];
    #pragma unroll
    for (int m = 0; m < 32; ++m)
        dt[(size_t)(row0 + m) * I_ + n] = softplusf(acc[m] + bv);
}

// ---------------------------------------------------------------------------
__global__ __launch_bounds__(256) void wtrans(
    const float* __restrict__ in, short* __restrict__ out,
    int Kd, int Nn, int Kpad, int Npad)
{
    __shared__ float t[32][33];
    const int n0 = blockIdx.x * 32, k0 = blockIdx.y * 32;
    const int tx = threadIdx.x, ty = threadIdx.y;
    #pragma unroll
    for (int j = 0; j < 32; j += 8) {
        int k = k0 + ty + j, n = n0 + tx;
        t[ty + j][tx] = (k < Kd && n < Nn) ? in[(size_t)k * Nn + n] : 0.f;
    }
    __syncthreads();
    #pragma unroll
    for (int j = 0; j < 32; j += 8) {
        int np = n0 + ty + j, kp = k0 + tx;
        if (np < Npad && kp < Kpad) out[(size_t)np * Kpad + kp] = f2bf(t[tx][ty + j]);
    }
}

__global__ __launch_bounds__(256) void cast_bf16(
    const float* __restrict__ in, short* __restrict__ out, int n4)
{
    int i = blockIdx.x * 256 + threadIdx.x;
    if (i >= n4) return;
    float4 v = ((const float4*)in)[i];
    out[i * 4 + 0] = f2bf(v.x); out[i * 4 + 1] = f2bf(v.y);
    out[i * 4 + 2] = f2bf(v.z); out[i * 4 + 3] = f2bf(v.w);
}

// ---------------------------------------------------------------------------
__global__ __launch_bounds__(256) void rmsnorm_bf16(
    const float* __restrict__ x, const float* __restrict__ w,
    short* __restrict__ out, int ncols)
{
    const int row = blockIdx.x;
    const float* xr = x + (size_t)row * ncols;
    float ss = 0.f;
    for (int c = threadIdx.x; c < ncols; c += 256) { float v = xr[c]; ss += v * v; }
    #pragma unroll
    for (int off = 32; off > 0; off >>= 1) ss += __shfl_down(ss, off, 64);
    __shared__ float red[4];
    __shared__ float stot;
    if ((threadIdx.x & 63) == 0) red[threadIdx.x >> 6] = ss;
    __syncthreads();
    if (threadIdx.x == 0) stot = red[0] + red[1] + red[2] + red[3];
    __syncthreads();
    const float scale = rsqrtf(stot / (float)ncols + EPS_);
    for (int c = threadIdx.x; c < ncols; c += 256)
        out[(size_t)row * ncols + c] = f2bf(xr[c] * scale * w[c]);
}

__global__ __launch_bounds__(256) void rmsnorm_f32(
    const float* __restrict__ x, const float* __restrict__ w,
    float* __restrict__ out, int ncols)
{
    const int row = blockIdx.x;
    const float* xr = x + (size_t)row * ncols;
    float ss = 0.f;
    for (int c = threadIdx.x; c < ncols; c += 256) { float v = xr[c]; ss += v * v; }
    #pragma unroll
    for (int off = 32; off > 0; off >>= 1) ss += __shfl_down(ss, off, 64);
    __shared__ float red[4];
    __shared__ float stot;
    if ((threadIdx.x & 63) == 0) red[threadIdx.x >> 6] = ss;
    __syncthreads();
    if (threadIdx.x == 0) stot = red[0] + red[1] + red[2] + red[3];
    __syncthreads();
    const float scale = rsqrtf(stot / (float)ncols + EPS_);
    for (int c = threadIdx.x; c < ncols; c += 256)
        out[(size_t)row * ncols + c] = xr[c] * scale * w[c];
}

// ---------------------------------------------------------------------------
__global__ __launch_bounds__(256) void conv_silu_kernel(
    const float* __restrict__ xz, const float* __restrict__ cw,
    const float* __restrict__ cb, float* __restrict__ xc,
    short* __restrict__ xcb16)
{
    int idx = blockIdx.x * 256 + threadIdx.x;
    if (idx >= MROWS * I_) return;
    int i  = idx % I_;
    int bs = idx / I_;
    int s  = bs % S_;
    int b  = bs / S_;
    const float* base = xz + (size_t)b * S_ * (2 * I_) + i;
    float acc = cb[i];
    #pragma unroll
    for (int k = 0; k < K_; ++k) {
        int ss = s - (K_ - 1) + k;
        if (ss >= 0) acc = fmaf(cw[i * K_ + k], base[(size_t)ss * (2 * I_)], acc);
    }
    float v = siluf(acc);
    xc[idx] = v;
    xcb16[idx] = f2bf(v);
}

// ---------------------------------------------------------------------------
// Chunk-parallel selective scan, 4 lanes/channel, 4 states/lane in registers.
// ---------------------------------------------------------------------------
__global__ __launch_bounds__(256) void scan_pass1(
    const float* __restrict__ xc, const float* __restrict__ dt,
    const float* __restrict__ dbc, const float* __restrict__ A_log,
    float* __restrict__ P, float* __restrict__ hend)
{
    __shared__ float Bsh[T_][16];
    const int tid = threadIdx.x;
    const int lc  = tid >> 2;
    const int sub = tid & 3;
    const int ib  = blockIdx.x % (I_ / 64);
    const int c   = (blockIdx.x / (I_ / 64)) % C_;
    const int b   = blockIdx.x / ((I_ / 64) * C_);
    const int i   = ib * 64 + lc;
    const int s0  = c * T_;

    for (int idx = tid; idx < T_ * 4; idx += 256) {
        int row = idx >> 2, q = idx & 3;
        *(float4*)&Bsh[row][q * 4] =
            *(const float4*)&dbc[((size_t)b * S_ + s0 + row) * 80 + R_ + q * 4];
    }

    float a[4], h[4] = {0.f, 0.f, 0.f, 0.f}, p[4] = {1.f, 1.f, 1.f, 1.f};
    #pragma unroll
    for (int j = 0; j < 4; ++j) a[j] = -expf(A_log[i * N_ + sub * 4 + j]);

    const float* dtp = dt + ((size_t)b * S_ + s0) * I_ + i;
    const float* xcp = xc + ((size_t)b * S_ + s0) * I_ + i;
    __syncthreads();

    float dtv = dtp[0], xcv = xcp[0];
    for (int s = 0; s < T_; ++s) {
        float dtn = 0.f, xcn = 0.f;
        if (s + 1 < T_) { dtn = dtp[(size_t)(s + 1) * I_]; xcn = xcp[(size_t)(s + 1) * I_]; }
        float4 Bv = *(const float4*)&Bsh[s][sub * 4];
        float dx = dtv * xcv;
        #pragma unroll
        for (int j = 0; j < 4; ++j) {
            float dA = expf(dtv * a[j]);
            float Bj = (j == 0) ? Bv.x : (j == 1) ? Bv.y : (j == 2) ? Bv.z : Bv.w;
            h[j] = fmaf(dA, h[j], dx * Bj);
            p[j] *= dA;
        }
        dtv = dtn; xcv = xcn;
    }
    size_t o = (((size_t)b * C_ + c) * I_ + i) * N_ + sub * 4;
    *(float4*)&P[o]    = (float4){p[0], p[1], p[2], p[3]};
    *(float4*)&hend[o] = (float4){h[0], h[1], h[2], h[3]};
}

__global__ __launch_bounds__(256) void scan_pass2(
    const float* __restrict__ P, const float* __restrict__ hend,
    float* __restrict__ Hstart)
{
    int idx = blockIdx.x * 256 + threadIdx.x;
    if (idx >= B_ * I_ * N_) return;
    int n = idx & 15;
    int i = (idx >> 4) % I_;
    int b = idx / (I_ * N_);
    float H = 0.f;
    #pragma unroll
    for (int c = 0; c < C_; ++c) {
        size_t o = (((size_t)b * C_ + c) * I_ + i) * (size_t)N_ + n;
        Hstart[o] = H;
        H = fmaf(P[o], H, hend[o]);
    }
}

__global__ __launch_bounds__(256) void scan_pass3(
    const float* __restrict__ xc, const float* __restrict__ dt,
    const float* __restrict__ dbc, const float* __restrict__ xz,
    const float* __restrict__ A_log, const float* __restrict__ D,
    const float* __restrict__ Hstart, short* __restrict__ y16)
{
    __shared__ float Bsh[T_][16];
    __shared__ float Csh[T_][16];
    const int tid = threadIdx.x;
    const int lc  = tid >> 2;
    const int sub = tid & 3;
    const int ib  = blockIdx.x % (I_ / 64);
    const int c   = (blockIdx.x / (I_ / 64)) % C_;
    const int b   = blockIdx.x / ((I_ / 64) * C_);
    const int i   = ib * 64 + lc;
    const int s0  = c * T_;

    for (int idx = tid; idx < T_ * 4; idx += 256) {
        int row = idx >> 2, q = idx & 3;
        const float* src = &dbc[((size_t)b * S_ + s0 + row) * 80 + R_];
        *(float4*)&Bsh[row][q * 4] = *(const float4*)&src[q * 4];
        *(float4*)&Csh[row][q * 4] = *(const float4*)&src[16 + q * 4];
    }

    float a[4], h[4];
    #pragma unroll
    for (int j = 0; j < 4; ++j) a[j] = -expf(A_log[i * N_ + sub * 4 + j]);
    const float Dv = D[i];

    size_t ho = (((size_t)b * C_ + c) * I_ + i) * N_ + sub * 4;
    float4 h0 = *(const float4*)&Hstart[ho];
    h[0] = h0.x; h[1] = h0.y; h[2] = h0.z; h[3] = h0.w;

    const float* dtp = dt  + ((size_t)b * S_ + s0) * I_ + i;
    const float* xcp = xc  + ((size_t)b * S_ + s0) * I_ + i;
    const float* zp  = xz  + ((size_t)b * S_ + s0) * (2 * I_) + I_ + i;
    short*       yp  = y16 + ((size_t)b * S_ + s0) * I_ + i;
    __syncthreads();

    float dtv = dtp[0], xcv = xcp[0];
    for (int s = 0; s < T_; ++s) {
        float dtn = 0.f, xcn = 0.f;
        if (s + 1 < T_) { dtn = dtp[(size_t)(s + 1) * I_]; xcn = xcp[(size_t)(s + 1) * I_]; }
        float4 Bv = *(const float4*)&Bsh[s][sub * 4];
        float4 Cv = *(const float4*)&Csh[s][sub * 4];
        float dx = dtv * xcv;
        float yv;
        {
            float dA0 = expf(dtv * a[0]);
            float dA1 = expf(dtv * a[1]);
            float dA2 = expf(dtv * a[2]);
            float dA3 = expf(dtv * a[3]);
            h[0] = fmaf(dA0, h[0], dx * Bv.x);
            h[1] = fmaf(dA1, h[1], dx * Bv.y);
            h[2] = fmaf(dA2, h[2], dx * Bv.z);
            h[3] = fmaf(dA3, h[3], dx * Bv.w);
            yv = h[0] * Cv.x;
            yv = fmaf(h[1], Cv.y, yv);
            yv = fmaf(h[2], Cv.z, yv);
            yv = fmaf(h[3], Cv.w, yv);
        }
        yv += __shfl_xor(yv, 1, 4);
        yv += __shfl_xor(yv, 2, 4);
        if (sub == 0) {
            float zv = zp[(size_t)s * (2 * I_)];
            yp[(size_t)s * I_] = f2bf((yv + xcv * Dv) * siluf(zv));
        }
        dtv = dtn; xcv = xcn;
    }
}

// ---------------------------------------------------------------------------
extern "C" void kernel_launch(void* const* d_in, const int* in_sizes, int n_in,
                              void* d_out, int out_size, void* d_ws, size_t ws_size,
                              hipStream_t stream)
{
    const float* x     = (const float*)d_in[0];
    const float* W_in  = (const float*)d_in[1];
    const float* b_in  = (const float*)d_in[2];
    const float* norm_w= (const float*)d_in[3];
    const float* ipw   = (const float*)d_in[4];
    const float* cw    = (const float*)d_in[5];
    const float* cb    = (const float*)d_in[6];
    const float* xpw   = (const float*)d_in[7];
    const float* dpw   = (const float*)d_in[8];
    const float* dpb   = (const float*)d_in[9];
    const float* A_log = (const float*)d_in[10];
    const float* Dp    = (const float*)d_in[11];
    const float* opw   = (const float*)d_in[12];
    const float* nfw   = (const float*)d_in[13];
    float* out = (float*)d_out;

    // fp32 scratch
    float* wsf  = (float*)d_ws;
    float* h    = wsf;  wsf += (size_t)MROWS * H_;
    float* xzb  = wsf;  wsf += (size_t)MROWS * 2 * I_;
    float* xcb  = wsf;  wsf += (size_t)MROWS * I_;
    float* dbcb = wsf;  wsf += (size_t)MROWS * 80;
    float* dtb  = wsf;  wsf += (size_t)MROWS * I_;
    float* Pb   = wsf;  wsf += (size_t)B_ * C_ * I_ * N_;
    float* heb  = wsf;  wsf += (size_t)B_ * C_ * I_ * N_;
    float* Hsb  = wsf;  wsf += (size_t)B_ * C_ * I_ * N_;
    // bf16 scratch
    short* wss   = (short*)wsf;
    short* x_bf  = wss;  wss += (size_t)MROWS * CIN_;
    short* u_bf  = wss;  wss += (size_t)MROWS * H_;
    short* xc_bf = wss;  wss += (size_t)MROWS * I_;
    short* y_bf  = wss;  wss += (size_t)MROWS * I_;
    short* WinT  = wss;  wss += (size_t)H_ * CIN_;
    short* ipwT  = wss;  wss += (size_t)L_ * 2 * I_ * H_;
    short* xpwT  = wss;  wss += (size_t)L_ * 128 * I_;
    short* opwT  = wss;  wss += (size_t)L_ * H_ * I_;

    // split-K partial aliases (dead at use time):
    float* part_Win = dtb;   // 2*2048*768  <= 2048*1536
    float* part_x   = dtb;   // 8*2048*80   <= 2048*1536
    float* part_o   = xzb;   // 3*2048*768  <= 2048*3072

    const dim3 blk(256);
    const dim3 tblk(32, 8);

    // one-time conversions
    cast_bf16<<<(MROWS * CIN_ / 4 + 255) / 256, blk, 0, stream>>>(x, x_bf, MROWS * CIN_ / 4);
    wtrans<<<dim3(H_ / 32, CIN_ / 32), tblk, 0, stream>>>(W_in, WinT, CIN_, H_, CIN_, H_);
    for (int l = 0; l < L_; ++l) {
        wtrans<<<dim3(2 * I_ / 32, H_ / 32), tblk, 0, stream>>>(
            ipw + (size_t)l * H_ * 2 * I_, ipwT + (size_t)l * 2 * I_ * H_, H_, 2 * I_, H_, 2 * I_);
        wtrans<<<dim3(128 / 32, I_ / 32), tblk, 0, stream>>>(
            xpw + (size_t)l * I_ * 80, xpwT + (size_t)l * 128 * I_, I_, 80, I_, 128);
        wtrans<<<dim3(H_ / 32, I_ / 32), tblk, 0, stream>>>(
            opw + (size_t)l * I_ * H_, opwT + (size_t)l * H_ * I_, I_, H_, I_, H_);
    }

    // h = x @ W_in + b_in   (split-K=2)
    gemm_mfma<<<dim3(H_ / 128, MROWS / 128, 2), blk, 0, stream>>>(
        x_bf, WinT, nullptr, part_Win, MROWS, H_, CIN_, CIN_, CIN_, H_, 0);
    reduce_parts<<<(MROWS * H_ + 255) / 256, blk, 0, stream>>>(
        part_Win, h, b_in, MROWS * H_, H_, 2, 1);

    const int scan_blocks = B_ * C_ * (I_ / 64);   // 1536

    for (int l = 0; l < L_; ++l) {
        rmsnorm_bf16<<<MROWS, blk, 0, stream>>>(h, norm_w + l * H_, u_bf, H_);
        gemm_mfma<<<dim3(2 * I_ / 128, MROWS / 128, 1), blk, 0, stream>>>(
            u_bf, ipwT + (size_t)l * 2 * I_ * H_, nullptr, xzb,
            MROWS, 2 * I_, H_, H_, H_, 2 * I_, 0);
        conv_silu_kernel<<<(MROWS * I_ + 255) / 256, blk, 0, stream>>>(
            xzb, cw + l * I_ * K_, cb + l * I_, xcb, xc_bf);
        gemm_mfma<<<dim3(1, MROWS / 128, 8), blk, 0, stream>>>(
            xc_bf, xpwT + (size_t)l * 128 * I_, nullptr, part_x,
            MROWS, 80, I_, I_, I_, 80, 0);
        reduce_parts<<<(MROWS * 80 + 255) / 256, blk, 0, stream>>>(
            part_x, dbcb, nullptr, MROWS * 80, 80, 8, 0);
        dt_kernel<<<dim3(I_ / 256, MROWS / 32), blk, 0, stream>>>(
            dbcb, dpw + (size_t)l * R_ * I_, dpb + l * I_, dtb);
        // chunked selective scan (register-state)
        scan_pass1<<<scan_blocks, blk, 0, stream>>>(
            xcb, dtb, dbcb, A_log + l * I_ * N_, Pb, heb);
        scan_pass2<<<(B_ * I_ * N_ + 255) / 256, blk, 0, stream>>>(Pb, heb, Hsb);
        scan_pass3<<<scan_blocks, blk, 0, stream>>>(
            xcb, dtb, dbcb, xzb, A_log + l * I_ * N_, Dp + l * I_, Hsb, y_bf);
        gemm_mfma<<<dim3(H_ / 128, MROWS / 128, 3), blk, 0, stream>>>(
            y_bf, opwT + (size_t)l * H_ * I_, nullptr, part_o,
            MROWS, H_, I_, I_, I_, H_, 0);
        reduce_parts<<<(MROWS * H_ + 255) / 256, blk, 0, stream>>>(
            part_o, h, nullptr, MROWS * H_, H_, 3, 2);
    }

    rmsnorm_f32<<<MROWS, blk, 0, stream>>>(h, nfw, out, H_);
}

// Round 9
// 910.861 us; speedup vs baseline: 5.3266x; 1.1669x over previous
//
#include <hip/hip_runtime.h>
#include <cmath>

#define B_    4
#define S_    512
#define CIN_  512
#define H_    768
#define I_    1536
#define N_    16
#define R_    48
#define K_    4
#define L_    4
#define EPS_  1e-5f
#define MROWS (B_ * S_)   // 2048
#define C_    16          // scan chunks
#define T_    (S_ / C_)   // 32 steps per chunk
#define DT_ROWS 8

typedef __attribute__((ext_vector_type(8))) short bf16x8;
typedef __attribute__((ext_vector_type(4))) float f32x4;

__device__ __forceinline__ float siluf(float x) { return x / (1.f + expf(-x)); }
__device__ __forceinline__ float softplusf(float x) { return x > 20.f ? x : log1pf(expf(x)); }
__device__ __forceinline__ short f2bf(float f) {
    union { float f; unsigned u; } v; v.f = f;
    unsigned r = v.u + 0x7fff + ((v.u >> 16) & 1);
    return (short)(r >> 16);
}

#define GLOAD16(g, l) __builtin_amdgcn_global_load_lds( \
    (const __attribute__((address_space(1))) void*)(g), \
    (__attribute__((address_space(3))) void*)(l), 16, 0, 0)

// ---------------------------------------------------------------------------
// bf16 MFMA GEMM: C[M,N] = A[M,K] @ Bt[N,K]^T  (128x128 tile, BK=32, 4 waves)
// gridDim.z > 1: split-K partials to C + z*M*ldc.  z==1: ep epilogues.
// ---------------------------------------------------------------------------
__global__ __launch_bounds__(256) void gemm_mfma(
    const short* __restrict__ A, const short* __restrict__ Bt,
    const float* __restrict__ bias, float* __restrict__ C,
    int M, int N, int Kd, int lda, int ldb, int ldc, int ep)
{
    __shared__ __align__(16) short Asl[128 * 32];
    __shared__ __align__(16) short Bsl[128 * 32];
    const int tid = threadIdx.x;
    const int ln  = tid & 63;
    const int wv  = tid >> 6;
    const int wm  = wv >> 1, wn = wv & 1;
    const int row0 = blockIdx.y * 128;
    const int col0 = blockIdx.x * 128;
    const int nz   = gridDim.z;
    const int kchunk = Kd / nz;
    const int kbeg   = blockIdx.z * kchunk;

    f32x4 acc[4][4];
    #pragma unroll
    for (int i = 0; i < 4; ++i)
        #pragma unroll
        for (int j = 0; j < 4; ++j) acc[i][j] = (f32x4){0.f, 0.f, 0.f, 0.f};

    const int c0 = tid, c1 = tid + 256;
    const short* ga0 = A  + (size_t)(row0 + (c0 >> 2)) * lda + (c0 & 3) * 8;
    const short* ga1 = A  + (size_t)(row0 + (c1 >> 2)) * lda + (c1 & 3) * 8;
    const short* gb0 = Bt + (size_t)(col0 + (c0 >> 2)) * ldb + (c0 & 3) * 8;
    const short* gb1 = Bt + (size_t)(col0 + (c1 >> 2)) * ldb + (c1 & 3) * 8;
    short* la0 = &Asl[(wv * 64) * 8];
    short* la1 = &Asl[(256 + wv * 64) * 8];
    short* lb0 = &Bsl[(wv * 64) * 8];
    short* lb1 = &Bsl[(256 + wv * 64) * 8];

    const int lrow = ln & 15;
    const int lk   = (ln >> 4) * 8;

    for (int k0 = kbeg; k0 < kbeg + kchunk; k0 += 32) {
        GLOAD16(ga0 + k0, la0);
        GLOAD16(ga1 + k0, la1);
        GLOAD16(gb0 + k0, lb0);
        GLOAD16(gb1 + k0, lb1);
        __syncthreads();
        bf16x8 af[4], bfr[4];
        #pragma unroll
        for (int fm = 0; fm < 4; ++fm)
            af[fm] = *(const bf16x8*)&Asl[(wm * 64 + fm * 16 + lrow) * 32 + lk];
        #pragma unroll
        for (int fn = 0; fn < 4; ++fn)
            bfr[fn] = *(const bf16x8*)&Bsl[(wn * 64 + fn * 16 + lrow) * 32 + lk];
        #pragma unroll
        for (int fm = 0; fm < 4; ++fm)
            #pragma unroll
            for (int fn = 0; fn < 4; ++fn)
                acc[fm][fn] = __builtin_amdgcn_mfma_f32_16x16x32_bf16(
                    af[fm], bfr[fn], acc[fm][fn], 0, 0, 0);
        __syncthreads();
    }

    const int erow = (ln >> 4) * 4;
    const int ecol = ln & 15;
    const size_t zoff = (size_t)blockIdx.z * M * ldc;
    #pragma unroll
    for (int fm = 0; fm < 4; ++fm) {
        #pragma unroll
        for (int fn = 0; fn < 4; ++fn) {
            int gn = col0 + wn * 64 + fn * 16 + ecol;
            if (gn >= N) continue;
            #pragma unroll
            for (int r = 0; r < 4; ++r) {
                int gm = row0 + wm * 64 + fm * 16 + erow + r;
                float v = acc[fm][fn][r];
                size_t o = (size_t)gm * ldc + gn;
                if (nz > 1) { C[zoff + o] = v; continue; }
                if (ep == 1)      v += bias[gn];
                else if (ep == 2) v  = softplusf(v + bias[gn]);
                else if (ep == 3) v += C[o];
                C[o] = v;
            }
        }
    }
}

// ---------------------------------------------------------------------------
__global__ __launch_bounds__(256) void reduce_parts(
    const float* __restrict__ part, float* __restrict__ C,
    const float* __restrict__ bias, int total, int ldc, int nz, int mode)
{
    int idx = blockIdx.x * 256 + threadIdx.x;
    if (idx >= total) return;
    size_t strideZ = (size_t)total;
    float s = 0.f;
    for (int z = 0; z < nz; ++z) s += part[idx + z * strideZ];
    if (mode == 1)      s += bias[idx % ldc];
    else if (mode == 2) s += C[idx];
    C[idx] = s;
}

// ---------------------------------------------------------------------------
// dt_proj fused: dt[m][n] = softplus(dbc[m][:48] @ dpwT[n][:48] + dpb[n]).
// dpwT is pre-transposed [I][48] fp32 -> per-thread weights contiguous.
// Block = 8 rows x 256 cols; 1536 blocks; weights in registers.
// ---------------------------------------------------------------------------
__global__ __launch_bounds__(256) void dt_kernel(
    const float* __restrict__ dbc, const float* __restrict__ dpwT,
    const float* __restrict__ dpb, float* __restrict__ dt)
{
    __shared__ float As[DT_ROWS][48];
    const int tid  = threadIdx.x;
    const int row0 = blockIdx.y * DT_ROWS;
    const int n    = blockIdx.x * 256 + tid;

    // issue weight loads first (independent, contiguous per thread)
    float4 wv[12];
    const float4* wp = (const float4*)(dpwT + (size_t)n * 48);
    #pragma unroll
    for (int q = 0; q < 12; ++q) wv[q] = wp[q];

    for (int idx = tid; idx < DT_ROWS * 48; idx += 256) {
        int m = idx / 48, k = idx - m * 48;
        As[m][k] = dbc[(size_t)(row0 + m) * 80 + k];
    }

    float wreg[48];
    #pragma unroll
    for (int q = 0; q < 12; ++q) {
        wreg[4 * q + 0] = wv[q].x; wreg[4 * q + 1] = wv[q].y;
        wreg[4 * q + 2] = wv[q].z; wreg[4 * q + 3] = wv[q].w;
    }
    __syncthreads();

    float acc[DT_ROWS] = {};
    #pragma unroll
    for (int k = 0; k < 48; ++k) {
        float w = wreg[k];
        #pragma unroll
        for (int m = 0; m < DT_ROWS; ++m)
            acc[m] = fmaf(As[m][k], w, acc[m]);
    }
    const float bv = dpb[n];
    #pragma unroll
    for (int m = 0; m < DT_ROWS; ++m)
        dt[(size_t)(row0 + m) * I_ + n] = softplusf(acc[m] + bv);
}

// ---------------------------------------------------------------------------
// fp32 transpose: in[Kd][Nn] -> out[Nn][Kd]
// ---------------------------------------------------------------------------
__global__ __launch_bounds__(256) void trans_f32(
    const float* __restrict__ in, float* __restrict__ out, int Kd, int Nn)
{
    __shared__ float t[32][33];
    const int n0 = blockIdx.x * 32, k0 = blockIdx.y * 32;
    const int tx = threadIdx.x, ty = threadIdx.y;
    #pragma unroll
    for (int j = 0; j < 32; j += 8) {
        int k = k0 + ty + j, n = n0 + tx;
        t[ty + j][tx] = (k < Kd && n < Nn) ? in[(size_t)k * Nn + n] : 0.f;
    }
    __syncthreads();
    #pragma unroll
    for (int j = 0; j < 32; j += 8) {
        int np = n0 + ty + j, kp = k0 + tx;
        if (np < Nn && kp < Kd) out[(size_t)np * Kd + kp] = t[tx][ty + j];
    }
}

// ---------------------------------------------------------------------------
__global__ __launch_bounds__(256) void wtrans(
    const float* __restrict__ in, short* __restrict__ out,
    int Kd, int Nn, int Kpad, int Npad)
{
    __shared__ float t[32][33];
    const int n0 = blockIdx.x * 32, k0 = blockIdx.y * 32;
    const int tx = threadIdx.x, ty = threadIdx.y;
    #pragma unroll
    for (int j = 0; j < 32; j += 8) {
        int k = k0 + ty + j, n = n0 + tx;
        t[ty + j][tx] = (k < Kd && n < Nn) ? in[(size_t)k * Nn + n] : 0.f;
    }
    __syncthreads();
    #pragma unroll
    for (int j = 0; j < 32; j += 8) {
        int np = n0 + ty + j, kp = k0 + tx;
        if (np < Npad && kp < Kpad) out[(size_t)np * Kpad + kp] = f2bf(t[tx][ty + j]);
    }
}

__global__ __launch_bounds__(256) void cast_bf16(
    const float* __restrict__ in, short* __restrict__ out, int n4)
{
    int i = blockIdx.x * 256 + threadIdx.x;
    if (i >= n4) return;
    float4 v = ((const float4*)in)[i];
    out[i * 4 + 0] = f2bf(v.x); out[i * 4 + 1] = f2bf(v.y);
    out[i * 4 + 2] = f2bf(v.z); out[i * 4 + 3] = f2bf(v.w);
}

// ---------------------------------------------------------------------------
__global__ __launch_bounds__(256) void rmsnorm_bf16(
    const float* __restrict__ x, const float* __restrict__ w,
    short* __restrict__ out, int ncols)
{
    const int row = blockIdx.x;
    const float* xr = x + (size_t)row * ncols;
    float ss = 0.f;
    for (int c = threadIdx.x; c < ncols; c += 256) { float v = xr[c]; ss += v * v; }
    #pragma unroll
    for (int off = 32; off > 0; off >>= 1) ss += __shfl_down(ss, off, 64);
    __shared__ float red[4];
    __shared__ float stot;
    if ((threadIdx.x & 63) == 0) red[threadIdx.x >> 6] = ss;
    __syncthreads();
    if (threadIdx.x == 0) stot = red[0] + red[1] + red[2] + red[3];
    __syncthreads();
    const float scale = rsqrtf(stot / (float)ncols + EPS_);
    for (int c = threadIdx.x; c < ncols; c += 256)
        out[(size_t)row * ncols + c] = f2bf(xr[c] * scale * w[c]);
}

__global__ __launch_bounds__(256) void rmsnorm_f32(
    const float* __restrict__ x, const float* __restrict__ w,
    float* __restrict__ out, int ncols)
{
    const int row = blockIdx.x;
    const float* xr = x + (size_t)row * ncols;
    float ss = 0.f;
    for (int c = threadIdx.x; c < ncols; c += 256) { float v = xr[c]; ss += v * v; }
    #pragma unroll
    for (int off = 32; off > 0; off >>= 1) ss += __shfl_down(ss, off, 64);
    __shared__ float red[4];
    __shared__ float stot;
    if ((threadIdx.x & 63) == 0) red[threadIdx.x >> 6] = ss;
    __syncthreads();
    if (threadIdx.x == 0) stot = red[0] + red[1] + red[2] + red[3];
    __syncthreads();
    const float scale = rsqrtf(stot / (float)ncols + EPS_);
    for (int c = threadIdx.x; c < ncols; c += 256)
        out[(size_t)row * ncols + c] = xr[c] * scale * w[c];
}

// ---------------------------------------------------------------------------
__global__ __launch_bounds__(256) void conv_silu_kernel(
    const float* __restrict__ xz, const float* __restrict__ cw,
    const float* __restrict__ cb, float* __restrict__ xc,
    short* __restrict__ xcb16)
{
    int idx = blockIdx.x * 256 + threadIdx.x;
    if (idx >= MROWS * I_) return;
    int i  = idx % I_;
    int bs = idx / I_;
    int s  = bs % S_;
    int b  = bs / S_;
    const float* base = xz + (size_t)b * S_ * (2 * I_) + i;
    float acc = cb[i];
    #pragma unroll
    for (int k = 0; k < K_; ++k) {
        int ss = s - (K_ - 1) + k;
        if (ss >= 0) acc = fmaf(cw[i * K_ + k], base[(size_t)ss * (2 * I_)], acc);
    }
    float v = siluf(acc);
    xc[idx] = v;
    xcb16[idx] = f2bf(v);
}

// ---------------------------------------------------------------------------
// Chunk-parallel selective scan, 4 lanes/channel, 4 states/lane in registers.
// ---------------------------------------------------------------------------
__global__ __launch_bounds__(256) void scan_pass1(
    const float* __restrict__ xc, const float* __restrict__ dt,
    const float* __restrict__ dbc, const float* __restrict__ A_log,
    float* __restrict__ P, float* __restrict__ hend)
{
    __shared__ float Bsh[T_][16];
    const int tid = threadIdx.x;
    const int lc  = tid >> 2;
    const int sub = tid & 3;
    const int ib  = blockIdx.x % (I_ / 64);
    const int c   = (blockIdx.x / (I_ / 64)) % C_;
    const int b   = blockIdx.x / ((I_ / 64) * C_);
    const int i   = ib * 64 + lc;
    const int s0  = c * T_;

    for (int idx = tid; idx < T_ * 4; idx += 256) {
        int row = idx >> 2, q = idx & 3;
        *(float4*)&Bsh[row][q * 4] =
            *(const float4*)&dbc[((size_t)b * S_ + s0 + row) * 80 + R_ + q * 4];
    }

    float a[4], h[4] = {0.f, 0.f, 0.f, 0.f}, p[4] = {1.f, 1.f, 1.f, 1.f};
    #pragma unroll
    for (int j = 0; j < 4; ++j) a[j] = -expf(A_log[i * N_ + sub * 4 + j]);

    const float* dtp = dt + ((size_t)b * S_ + s0) * I_ + i;
    const float* xcp = xc + ((size_t)b * S_ + s0) * I_ + i;
    __syncthreads();

    float dtv = dtp[0], xcv = xcp[0];
    for (int s = 0; s < T_; ++s) {
        float dtn = 0.f, xcn = 0.f;
        if (s + 1 < T_) { dtn = dtp[(size_t)(s + 1) * I_]; xcn = xcp[(size_t)(s + 1) * I_]; }
        float4 Bv = *(const float4*)&Bsh[s][sub * 4];
        float dx = dtv * xcv;
        #pragma unroll
        for (int j = 0; j < 4; ++j) {
            float dA = expf(dtv * a[j]);
            float Bj = (j == 0) ? Bv.x : (j == 1) ? Bv.y : (j == 2) ? Bv.z : Bv.w;
            h[j] = fmaf(dA, h[j], dx * Bj);
            p[j] *= dA;
        }
        dtv = dtn; xcv = xcn;
    }
    size_t o = (((size_t)b * C_ + c) * I_ + i) * N_ + sub * 4;
    *(float4*)&P[o]    = (float4){p[0], p[1], p[2], p[3]};
    *(float4*)&hend[o] = (float4){h[0], h[1], h[2], h[3]};
}

__global__ __launch_bounds__(256) void scan_pass2(
    const float* __restrict__ P, const float* __restrict__ hend,
    float* __restrict__ Hstart)
{
    int idx = blockIdx.x * 256 + threadIdx.x;
    if (idx >= B_ * I_ * N_) return;
    int n = idx & 15;
    int i = (idx >> 4) % I_;
    int b = idx / (I_ * N_);
    float H = 0.f;
    #pragma unroll
    for (int c = 0; c < C_; ++c) {
        size_t o = (((size_t)b * C_ + c) * I_ + i) * (size_t)N_ + n;
        Hstart[o] = H;
        H = fmaf(P[o], H, hend[o]);
    }
}

__global__ __launch_bounds__(256) void scan_pass3(
    const float* __restrict__ xc, const float* __restrict__ dt,
    const float* __restrict__ dbc, const float* __restrict__ xz,
    const float* __restrict__ A_log, const float* __restrict__ D,
    const float* __restrict__ Hstart, short* __restrict__ y16)
{
    __shared__ float Bsh[T_][16];
    __shared__ float Csh[T_][16];
    const int tid = threadIdx.x;
    const int lc  = tid >> 2;
    const int sub = tid & 3;
    const int ib  = blockIdx.x % (I_ / 64);
    const int c   = (blockIdx.x / (I_ / 64)) % C_;
    const int b   = blockIdx.x / ((I_ / 64) * C_);
    const int i   = ib * 64 + lc;
    const int s0  = c * T_;

    for (int idx = tid; idx < T_ * 4; idx += 256) {
        int row = idx >> 2, q = idx & 3;
        const float* src = &dbc[((size_t)b * S_ + s0 + row) * 80 + R_];
        *(float4*)&Bsh[row][q * 4] = *(const float4*)&src[q * 4];
        *(float4*)&Csh[row][q * 4] = *(const float4*)&src[16 + q * 4];
    }

    float a[4], h[4];
    #pragma unroll
    for (int j = 0; j < 4; ++j) a[j] = -expf(A_log[i * N_ + sub * 4 + j]);
    const float Dv = D[i];

    size_t ho = (((size_t)b * C_ + c) * I_ + i) * N_ + sub * 4;
    float4 h0 = *(const float4*)&Hstart[ho];
    h[0] = h0.x; h[1] = h0.y; h[2] = h0.z; h[3] = h0.w;

    const float* dtp = dt  + ((size_t)b * S_ + s0) * I_ + i;
    const float* xcp = xc  + ((size_t)b * S_ + s0) * I_ + i;
    const float* zp  = xz  + ((size_t)b * S_ + s0) * (2 * I_) + I_ + i;
    short*       yp  = y16 + ((size_t)b * S_ + s0) * I_ + i;
    __syncthreads();

    float dtv = dtp[0], xcv = xcp[0];
    for (int s = 0; s < T_; ++s) {
        float dtn = 0.f, xcn = 0.f;
        if (s + 1 < T_) { dtn = dtp[(size_t)(s + 1) * I_]; xcn = xcp[(size_t)(s + 1) * I_]; }
        float4 Bv = *(const float4*)&Bsh[s][sub * 4];
        float4 Cv = *(const float4*)&Csh[s][sub * 4];
        float dx = dtv * xcv;
        float yv;
        {
            float dA0 = expf(dtv * a[0]);
            float dA1 = expf(dtv * a[1]);
            float dA2 = expf(dtv * a[2]);
            float dA3 = expf(dtv * a[3]);
            h[0] = fmaf(dA0, h[0], dx * Bv.x);
            h[1] = fmaf(dA1, h[1], dx * Bv.y);
            h[2] = fmaf(dA2, h[2], dx * Bv.z);
            h[3] = fmaf(dA3, h[3], dx * Bv.w);
            yv = h[0] * Cv.x;
            yv = fmaf(h[1], Cv.y, yv);
            yv = fmaf(h[2], Cv.z, yv);
            yv = fmaf(h[3], Cv.w, yv);
        }
        yv += __shfl_xor(yv, 1, 4);
        yv += __shfl_xor(yv, 2, 4);
        if (sub == 0) {
            float zv = zp[(size_t)s * (2 * I_)];
            yp[(size_t)s * I_] = f2bf((yv + xcv * Dv) * siluf(zv));
        }
        dtv = dtn; xcv = xcn;
    }
}

// ---------------------------------------------------------------------------
extern "C" void kernel_launch(void* const* d_in, const int* in_sizes, int n_in,
                              void* d_out, int out_size, void* d_ws, size_t ws_size,
                              hipStream_t stream)
{
    const float* x     = (const float*)d_in[0];
    const float* W_in  = (const float*)d_in[1];
    const float* b_in  = (const float*)d_in[2];
    const float* norm_w= (const float*)d_in[3];
    const float* ipw   = (const float*)d_in[4];
    const float* cw    = (const float*)d_in[5];
    const float* cb    = (const float*)d_in[6];
    const float* xpw   = (const float*)d_in[7];
    const float* dpw   = (const float*)d_in[8];
    const float* dpb   = (const float*)d_in[9];
    const float* A_log = (const float*)d_in[10];
    const float* Dp    = (const float*)d_in[11];
    const float* opw   = (const float*)d_in[12];
    const float* nfw   = (const float*)d_in[13];
    float* out = (float*)d_out;

    // fp32 scratch
    float* wsf  = (float*)d_ws;
    float* h    = wsf;  wsf += (size_t)MROWS * H_;
    float* xzb  = wsf;  wsf += (size_t)MROWS * 2 * I_;
    float* xcb  = wsf;  wsf += (size_t)MROWS * I_;
    float* dbcb = wsf;  wsf += (size_t)MROWS * 80;
    float* dtb  = wsf;  wsf += (size_t)MROWS * I_;
    float* Pb   = wsf;  wsf += (size_t)B_ * C_ * I_ * N_;
    float* heb  = wsf;  wsf += (size_t)B_ * C_ * I_ * N_;
    float* Hsb  = wsf;  wsf += (size_t)B_ * C_ * I_ * N_;
    float* dpwTf= wsf;  wsf += (size_t)L_ * I_ * R_;
    // bf16 scratch
    short* wss   = (short*)wsf;
    short* x_bf  = wss;  wss += (size_t)MROWS * CIN_;
    short* u_bf  = wss;  wss += (size_t)MROWS * H_;
    short* xc_bf = wss;  wss += (size_t)MROWS * I_;
    short* y_bf  = wss;  wss += (size_t)MROWS * I_;
    short* WinT  = wss;  wss += (size_t)H_ * CIN_;
    short* ipwT  = wss;  wss += (size_t)L_ * 2 * I_ * H_;
    short* xpwT  = wss;  wss += (size_t)L_ * 128 * I_;
    short* opwT  = wss;  wss += (size_t)L_ * H_ * I_;

    // split-K partial aliases (dead at use time):
    float* part_Win = dtb;   // 2*2048*768  <= 2048*1536
    float* part_x   = dtb;   // 8*2048*80   <= 2048*1536
    float* part_o   = xzb;   // 3*2048*768  <= 2048*3072

    const dim3 blk(256);
    const dim3 tblk(32, 8);

    // one-time conversions
    cast_bf16<<<(MROWS * CIN_ / 4 + 255) / 256, blk, 0, stream>>>(x, x_bf, MROWS * CIN_ / 4);
    wtrans<<<dim3(H_ / 32, CIN_ / 32), tblk, 0, stream>>>(W_in, WinT, CIN_, H_, CIN_, H_);
    for (int l = 0; l < L_; ++l) {
        wtrans<<<dim3(2 * I_ / 32, H_ / 32), tblk, 0, stream>>>(
            ipw + (size_t)l * H_ * 2 * I_, ipwT + (size_t)l * 2 * I_ * H_, H_, 2 * I_, H_, 2 * I_);
        wtrans<<<dim3(128 / 32, I_ / 32), tblk, 0, stream>>>(
            xpw + (size_t)l * I_ * 80, xpwT + (size_t)l * 128 * I_, I_, 80, I_, 128);
        wtrans<<<dim3(H_ / 32, I_ / 32), tblk, 0, stream>>>(
            opw + (size_t)l * I_ * H_, opwT + (size_t)l * H_ * I_, I_, H_, I_, H_);
        trans_f32<<<dim3(I_ / 32, 2), tblk, 0, stream>>>(
            dpw + (size_t)l * R_ * I_, dpwTf + (size_t)l * I_ * R_, R_, I_);
    }

    // h = x @ W_in + b_in   (split-K=2)
    gemm_mfma<<<dim3(H_ / 128, MROWS / 128, 2), blk, 0, stream>>>(
        x_bf, WinT, nullptr, part_Win, MROWS, H_, CIN_, CIN_, CIN_, H_, 0);
    reduce_parts<<<(MROWS * H_ + 255) / 256, blk, 0, stream>>>(
        part_Win, h, b_in, MROWS * H_, H_, 2, 1);

    const int scan_blocks = B_ * C_ * (I_ / 64);   // 1536

    for (int l = 0; l < L_; ++l) {
        rmsnorm_bf16<<<MROWS, blk, 0, stream>>>(h, norm_w + l * H_, u_bf, H_);
        gemm_mfma<<<dim3(2 * I_ / 128, MROWS / 128, 1), blk, 0, stream>>>(
            u_bf, ipwT + (size_t)l * 2 * I_ * H_, nullptr, xzb,
            MROWS, 2 * I_, H_, H_, H_, 2 * I_, 0);
        conv_silu_kernel<<<(MROWS * I_ + 255) / 256, blk, 0, stream>>>(
            xzb, cw + l * I_ * K_, cb + l * I_, xcb, xc_bf);
        gemm_mfma<<<dim3(1, MROWS / 128, 8), blk, 0, stream>>>(
            xc_bf, xpwT + (size_t)l * 128 * I_, nullptr, part_x,
            MROWS, 80, I_, I_, I_, 80, 0);
        reduce_parts<<<(MROWS * 80 + 255) / 256, blk, 0, stream>>>(
            part_x, dbcb, nullptr, MROWS * 80, 80, 8, 0);
        dt_kernel<<<dim3(I_ / 256, MROWS / DT_ROWS), blk, 0, stream>>>(
            dbcb, dpwTf + (size_t)l * I_ * R_, dpb + l * I_, dtb);
        // chunked selective scan (register-state)
        scan_pass1<<<scan_blocks, blk, 0, stream>>>(
            xcb, dtb, dbcb, A_log + l * I_ * N_, Pb, heb);
        scan_pass2<<<(B_ * I_ * N_ + 255) / 256, blk, 0, stream>>>(Pb, heb, Hsb);
        scan_pass3<<<scan_blocks, blk, 0, stream>>>(
            xcb, dtb, dbcb, xzb, A_log + l * I_ * N_, Dp + l * I_, Hsb, y_bf);
        gemm_mfma<<<dim3(H_ / 128, MROWS / 128, 3), blk, 0, stream>>>(
            y_bf, opwT + (size_t)l * H_ * I_, nullptr, part_o,
            MROWS, H_, I_, I_, I_, H_, 0);
        reduce_parts<<<(MROWS * H_ + 255) / 256, blk, 0, stream>>>(
            part_o, h, nullptr, MROWS * H_, H_, 3, 2);
    }

    rmsnorm_f32<<<MROWS, blk, 0, stream>>>(h, nfw, out, H_);
}

// Round 10
// 847.931 us; speedup vs baseline: 5.7219x; 1.0742x over previous
//
#include <hip/hip_runtime.h>
#include <cmath>

#define B_    4
#define S_    512
#define CIN_  512
#define H_    768
#define I_    1536
#define N_    16
#define R_    48
#define K_    4
#define L_    4
#define EPS_  1e-5f
#define MROWS (B_ * S_)   // 2048
#define C_    16          // scan chunks
#define T_    (S_ / C_)   // 32 steps per chunk
#define DT_ROWS 8

typedef __attribute__((ext_vector_type(8))) short bf16x8;
typedef __attribute__((ext_vector_type(4))) float f32x4;

__device__ __forceinline__ float siluf(float x) { return x / (1.f + expf(-x)); }
__device__ __forceinline__ float softplusf(float x) { return x > 20.f ? x : log1pf(expf(x)); }
__device__ __forceinline__ short f2bf(float f) {
    union { float f; unsigned u; } v; v.f = f;
    unsigned r = v.u + 0x7fff + ((v.u >> 16) & 1);
    return (short)(r >> 16);
}

#define GLOAD16(g, l) __builtin_amdgcn_global_load_lds( \
    (const __attribute__((address_space(1))) void*)(g), \
    (__attribute__((address_space(3))) void*)(l), 16, 0, 0)

// ---------------------------------------------------------------------------
// bf16 MFMA GEMM: C[M,N] = A[M,K] @ Bt[N,K]^T
// 64x128 tile, BK=32, 256 threads = 4 waves (2x2); each wave 32x64 (2x4 frags).
// LDS layout swizzle: chunk c holds global kpart (c&3)^(row&3) of row c>>2
// (same-involution on stage-source and read -> conflict reduction, rule #21).
// gridDim.z > 1: split-K partials to C + z*M*ldc.  z==1: ep epilogues:
//   0 none; 1 +bias; 2 softplus(v+bias); 3 C += v.
// ---------------------------------------------------------------------------
__global__ __launch_bounds__(256) void gemm_mfma(
    const short* __restrict__ A, const short* __restrict__ Bt,
    const float* __restrict__ bias, float* __restrict__ C,
    int M, int N, int Kd, int lda, int ldb, int ldc, int ep)
{
    __shared__ __align__(16) short Asl[64 * 32];
    __shared__ __align__(16) short Bsl[128 * 32];
    const int tid = threadIdx.x;
    const int ln  = tid & 63;
    const int wv  = tid >> 6;
    const int wm  = wv >> 1, wn = wv & 1;
    const int row0 = blockIdx.y * 64;
    const int col0 = blockIdx.x * 128;
    const int nz   = gridDim.z;
    const int kchunk = Kd / nz;
    const int kbeg   = blockIdx.z * kchunk;

    f32x4 acc[2][4];
    #pragma unroll
    for (int i = 0; i < 2; ++i)
        #pragma unroll
        for (int j = 0; j < 4; ++j) acc[i][j] = (f32x4){0.f, 0.f, 0.f, 0.f};

    // A staging: 256 chunks (64 rows x 4 kparts), one per thread.
    const int ca   = tid;
    const int rowa = ca >> 2;
    const int kpa  = (ca & 3) ^ (rowa & 3);
    const short* ga = A + (size_t)(row0 + rowa) * lda + kpa * 8;
    short* la = &Asl[(wv * 64) * 8];
    // B staging: 512 chunks, two per thread.
    const int cb0 = tid, cb1 = tid + 256;
    const int rowb0 = cb0 >> 2, kpb0 = (cb0 & 3) ^ (rowb0 & 3);
    const int rowb1 = cb1 >> 2, kpb1 = (cb1 & 3) ^ (rowb1 & 3);
    const short* gb0 = Bt + (size_t)(col0 + rowb0) * ldb + kpb0 * 8;
    const short* gb1 = Bt + (size_t)(col0 + rowb1) * ldb + kpb1 * 8;
    short* lb0 = &Bsl[(wv * 64) * 8];
    short* lb1 = &Bsl[(256 + wv * 64) * 8];

    const int lrow = ln & 15;
    const int kq   = ln >> 4;

    for (int k0 = kbeg; k0 < kbeg + kchunk; k0 += 32) {
        GLOAD16(ga + k0, la);
        GLOAD16(gb0 + k0, lb0);
        GLOAD16(gb1 + k0, lb1);
        __syncthreads();
        bf16x8 af[2], bfr[4];
        #pragma unroll
        for (int fm = 0; fm < 2; ++fm) {
            int r = wm * 32 + fm * 16 + lrow;
            int slot = r * 4 + (kq ^ (r & 3));
            af[fm] = *(const bf16x8*)&Asl[slot * 8];
        }
        #pragma unroll
        for (int fn = 0; fn < 4; ++fn) {
            int r = wn * 64 + fn * 16 + lrow;
            int slot = r * 4 + (kq ^ (r & 3));
            bfr[fn] = *(const bf16x8*)&Bsl[slot * 8];
        }
        #pragma unroll
        for (int fm = 0; fm < 2; ++fm)
            #pragma unroll
            for (int fn = 0; fn < 4; ++fn)
                acc[fm][fn] = __builtin_amdgcn_mfma_f32_16x16x32_bf16(
                    af[fm], bfr[fn], acc[fm][fn], 0, 0, 0);
        __syncthreads();
    }

    const int erow = (ln >> 4) * 4;
    const int ecol = ln & 15;
    const size_t zoff = (size_t)blockIdx.z * M * ldc;
    #pragma unroll
    for (int fm = 0; fm < 2; ++fm) {
        #pragma unroll
        for (int fn = 0; fn < 4; ++fn) {
            int gn = col0 + wn * 64 + fn * 16 + ecol;
            if (gn >= N) continue;
            #pragma unroll
            for (int r = 0; r < 4; ++r) {
                int gm = row0 + wm * 32 + fm * 16 + erow + r;
                float v = acc[fm][fn][r];
                size_t o = (size_t)gm * ldc + gn;
                if (nz > 1) { C[zoff + o] = v; continue; }
                if (ep == 1)      v += bias[gn];
                else if (ep == 2) v  = softplusf(v + bias[gn]);
                else if (ep == 3) v += C[o];
                C[o] = v;
            }
        }
    }
}

// ---------------------------------------------------------------------------
__global__ __launch_bounds__(256) void reduce_parts(
    const float* __restrict__ part, float* __restrict__ C,
    const float* __restrict__ bias, int total, int ldc, int nz, int mode)
{
    int idx = blockIdx.x * 256 + threadIdx.x;
    if (idx >= total) return;
    size_t strideZ = (size_t)total;
    float s = 0.f;
    for (int z = 0; z < nz; ++z) s += part[idx + z * strideZ];
    if (mode == 1)      s += bias[idx % ldc];
    else if (mode == 2) s += C[idx];
    C[idx] = s;
}

// ---------------------------------------------------------------------------
// dt_proj fused: dt[m][n] = softplus(dbc[m][:48] @ dpwT[n][:48] + dpb[n]).
// ---------------------------------------------------------------------------
__global__ __launch_bounds__(256) void dt_kernel(
    const float* __restrict__ dbc, const float* __restrict__ dpwT,
    const float* __restrict__ dpb, float* __restrict__ dt)
{
    __shared__ float As[DT_ROWS][48];
    const int tid  = threadIdx.x;
    const int row0 = blockIdx.y * DT_ROWS;
    const int n    = blockIdx.x * 256 + tid;

    float4 wv[12];
    const float4* wp = (const float4*)(dpwT + (size_t)n * 48);
    #pragma unroll
    for (int q = 0; q < 12; ++q) wv[q] = wp[q];

    for (int idx = tid; idx < DT_ROWS * 48; idx += 256) {
        int m = idx / 48, k = idx - m * 48;
        As[m][k] = dbc[(size_t)(row0 + m) * 80 + k];
    }

    float wreg[48];
    #pragma unroll
    for (int q = 0; q < 12; ++q) {
        wreg[4 * q + 0] = wv[q].x; wreg[4 * q + 1] = wv[q].y;
        wreg[4 * q + 2] = wv[q].z; wreg[4 * q + 3] = wv[q].w;
    }
    __syncthreads();

    float acc[DT_ROWS] = {};
    #pragma unroll
    for (int k = 0; k < 48; ++k) {
        float w = wreg[k];
        #pragma unroll
        for (int m = 0; m < DT_ROWS; ++m)
            acc[m] = fmaf(As[m][k], w, acc[m]);
    }
    const float bv = dpb[n];
    #pragma unroll
    for (int m = 0; m < DT_ROWS; ++m)
        dt[(size_t)(row0 + m) * I_ + n] = softplusf(acc[m] + bv);
}

// ---------------------------------------------------------------------------
__global__ __launch_bounds__(256) void trans_f32(
    const float* __restrict__ in, float* __restrict__ out, int Kd, int Nn)
{
    __shared__ float t[32][33];
    const int n0 = blockIdx.x * 32, k0 = blockIdx.y * 32;
    const int tx = threadIdx.x, ty = threadIdx.y;
    #pragma unroll
    for (int j = 0; j < 32; j += 8) {
        int k = k0 + ty + j, n = n0 + tx;
        t[ty + j][tx] = (k < Kd && n < Nn) ? in[(size_t)k * Nn + n] : 0.f;
    }
    __syncthreads();
    #pragma unroll
    for (int j = 0; j < 32; j += 8) {
        int np = n0 + ty + j, kp = k0 + tx;
        if (np < Nn && kp < Kd) out[(size_t)np * Kd + kp] = t[tx][ty + j];
    }
}

// ---------------------------------------------------------------------------
__global__ __launch_bounds__(256) void wtrans(
    const float* __restrict__ in, short* __restrict__ out,
    int Kd, int Nn, int Kpad, int Npad)
{
    __shared__ float t[32][33];
    const int n0 = blockIdx.x * 32, k0 = blockIdx.y * 32;
    const int tx = threadIdx.x, ty = threadIdx.y;
    #pragma unroll
    for (int j = 0; j < 32; j += 8) {
        int k = k0 + ty + j, n = n0 + tx;
        t[ty + j][tx] = (k < Kd && n < Nn) ? in[(size_t)k * Nn + n] : 0.f;
    }
    __syncthreads();
    #pragma unroll
    for (int j = 0; j < 32; j += 8) {
        int np = n0 + ty + j, kp = k0 + tx;
        if (np < Npad && kp < Kpad) out[(size_t)np * Kpad + kp] = f2bf(t[tx][ty + j]);
    }
}

__global__ __launch_bounds__(256) void cast_bf16(
    const float* __restrict__ in, short* __restrict__ out, int n4)
{
    int i = blockIdx.x * 256 + threadIdx.x;
    if (i >= n4) return;
    float4 v = ((const float4*)in)[i];
    out[i * 4 + 0] = f2bf(v.x); out[i * 4 + 1] = f2bf(v.y);
    out[i * 4 + 2] = f2bf(v.z); out[i * 4 + 3] = f2bf(v.w);
}

// ---------------------------------------------------------------------------
__global__ __launch_bounds__(256) void rmsnorm_bf16(
    const float* __restrict__ x, const float* __restrict__ w,
    short* __restrict__ out, int ncols)
{
    const int row = blockIdx.x;
    const float* xr = x + (size_t)row * ncols;
    float ss = 0.f;
    for (int c = threadIdx.x; c < ncols; c += 256) { float v = xr[c]; ss += v * v; }
    #pragma unroll
    for (int off = 32; off > 0; off >>= 1) ss += __shfl_down(ss, off, 64);
    __shared__ float red[4];
    __shared__ float stot;
    if ((threadIdx.x & 63) == 0) red[threadIdx.x >> 6] = ss;
    __syncthreads();
    if (threadIdx.x == 0) stot = red[0] + red[1] + red[2] + red[3];
    __syncthreads();
    const float scale = rsqrtf(stot / (float)ncols + EPS_);
    for (int c = threadIdx.x; c < ncols; c += 256)
        out[(size_t)row * ncols + c] = f2bf(xr[c] * scale * w[c]);
}

__global__ __launch_bounds__(256) void rmsnorm_f32(
    const float* __restrict__ x, const float* __restrict__ w,
    float* __restrict__ out, int ncols)
{
    const int row = blockIdx.x;
    const float* xr = x + (size_t)row * ncols;
    float ss = 0.f;
    for (int c = threadIdx.x; c < ncols; c += 256) { float v = xr[c]; ss += v * v; }
    #pragma unroll
    for (int off = 32; off > 0; off >>= 1) ss += __shfl_down(ss, off, 64);
    __shared__ float red[4];
    __shared__ float stot;
    if ((threadIdx.x & 63) == 0) red[threadIdx.x >> 6] = ss;
    __syncthreads();
    if (threadIdx.x == 0) stot = red[0] + red[1] + red[2] + red[3];
    __syncthreads();
    const float scale = rsqrtf(stot / (float)ncols + EPS_);
    for (int c = threadIdx.x; c < ncols; c += 256)
        out[(size_t)row * ncols + c] = xr[c] * scale * w[c];
}

// ---------------------------------------------------------------------------
__global__ __launch_bounds__(256) void conv_silu_kernel(
    const float* __restrict__ xz, const float* __restrict__ cw,
    const float* __restrict__ cb, float* __restrict__ xc,
    short* __restrict__ xcb16)
{
    int idx = blockIdx.x * 256 + threadIdx.x;
    if (idx >= MROWS * I_) return;
    int i  = idx % I_;
    int bs = idx / I_;
    int s  = bs % S_;
    int b  = bs / S_;
    const float* base = xz + (size_t)b * S_ * (2 * I_) + i;
    float acc = cb[i];
    #pragma unroll
    for (int k = 0; k < K_; ++k) {
        int ss = s - (K_ - 1) + k;
        if (ss >= 0) acc = fmaf(cw[i * K_ + k], base[(size_t)ss * (2 * I_)], acc);
    }
    float v = siluf(acc);
    xc[idx] = v;
    xcb16[idx] = f2bf(v);
}

// ---------------------------------------------------------------------------
// Chunk-parallel selective scan, 4 lanes/channel, 4 states/lane in registers.
// ---------------------------------------------------------------------------
__global__ __launch_bounds__(256) void scan_pass1(
    const float* __restrict__ xc, const float* __restrict__ dt,
    const float* __restrict__ dbc, const float* __restrict__ A_log,
    float* __restrict__ P, float* __restrict__ hend)
{
    __shared__ float Bsh[T_][16];
    const int tid = threadIdx.x;
    const int lc  = tid >> 2;
    const int sub = tid & 3;
    const int ib  = blockIdx.x % (I_ / 64);
    const int c   = (blockIdx.x / (I_ / 64)) % C_;
    const int b   = blockIdx.x / ((I_ / 64) * C_);
    const int i   = ib * 64 + lc;
    const int s0  = c * T_;

    for (int idx = tid; idx < T_ * 4; idx += 256) {
        int row = idx >> 2, q = idx & 3;
        *(float4*)&Bsh[row][q * 4] =
            *(const float4*)&dbc[((size_t)b * S_ + s0 + row) * 80 + R_ + q * 4];
    }

    float a[4], h[4] = {0.f, 0.f, 0.f, 0.f}, p[4] = {1.f, 1.f, 1.f, 1.f};
    #pragma unroll
    for (int j = 0; j < 4; ++j) a[j] = -expf(A_log[i * N_ + sub * 4 + j]);

    const float* dtp = dt + ((size_t)b * S_ + s0) * I_ + i;
    const float* xcp = xc + ((size_t)b * S_ + s0) * I_ + i;
    __syncthreads();

    float dtv = dtp[0], xcv = xcp[0];
    for (int s = 0; s < T_; ++s) {
        float dtn = 0.f, xcn = 0.f;
        if (s + 1 < T_) { dtn = dtp[(size_t)(s + 1) * I_]; xcn = xcp[(size_t)(s + 1) * I_]; }
        float4 Bv = *(const float4*)&Bsh[s][sub * 4];
        float dx = dtv * xcv;
        #pragma unroll
        for (int j = 0; j < 4; ++j) {
            float dA = expf(dtv * a[j]);
            float Bj = (j == 0) ? Bv.x : (j == 1) ? Bv.y : (j == 2) ? Bv.z : Bv.w;
            h[j] = fmaf(dA, h[j], dx * Bj);
            p[j] *= dA;
        }
        dtv = dtn; xcv = xcn;
    }
    size_t o = (((size_t)b * C_ + c) * I_ + i) * N_ + sub * 4;
    *(float4*)&P[o]    = (float4){p[0], p[1], p[2], p[3]};
    *(float4*)&hend[o] = (float4){h[0], h[1], h[2], h[3]};
}

__global__ __launch_bounds__(256) void scan_pass2(
    const float* __restrict__ P, const float* __restrict__ hend,
    float* __restrict__ Hstart)
{
    int idx = blockIdx.x * 256 + threadIdx.x;
    if (idx >= B_ * I_ * N_) return;
    int n = idx & 15;
    int i = (idx >> 4) % I_;
    int b = idx / (I_ * N_);
    float H = 0.f;
    #pragma unroll
    for (int c = 0; c < C_; ++c) {
        size_t o = (((size_t)b * C_ + c) * I_ + i) * (size_t)N_ + n;
        Hstart[o] = H;
        H = fmaf(P[o], H, hend[o]);
    }
}

__global__ __launch_bounds__(256) void scan_pass3(
    const float* __restrict__ xc, const float* __restrict__ dt,
    const float* __restrict__ dbc, const float* __restrict__ xz,
    const float* __restrict__ A_log, const float* __restrict__ D,
    const float* __restrict__ Hstart, short* __restrict__ y16)
{
    __shared__ float Bsh[T_][16];
    __shared__ float Csh[T_][16];
    const int tid = threadIdx.x;
    const int lc  = tid >> 2;
    const int sub = tid & 3;
    const int ib  = blockIdx.x % (I_ / 64);
    const int c   = (blockIdx.x / (I_ / 64)) % C_;
    const int b   = blockIdx.x / ((I_ / 64) * C_);
    const int i   = ib * 64 + lc;
    const int s0  = c * T_;

    for (int idx = tid; idx < T_ * 4; idx += 256) {
        int row = idx >> 2, q = idx & 3;
        const float* src = &dbc[((size_t)b * S_ + s0 + row) * 80 + R_];
        *(float4*)&Bsh[row][q * 4] = *(const float4*)&src[q * 4];
        *(float4*)&Csh[row][q * 4] = *(const float4*)&src[16 + q * 4];
    }

    float a[4], h[4];
    #pragma unroll
    for (int j = 0; j < 4; ++j) a[j] = -expf(A_log[i * N_ + sub * 4 + j]);
    const float Dv = D[i];

    size_t ho = (((size_t)b * C_ + c) * I_ + i) * N_ + sub * 4;
    float4 h0 = *(const float4*)&Hstart[ho];
    h[0] = h0.x; h[1] = h0.y; h[2] = h0.z; h[3] = h0.w;

    const float* dtp = dt  + ((size_t)b * S_ + s0) * I_ + i;
    const float* xcp = xc  + ((size_t)b * S_ + s0) * I_ + i;
    const float* zp  = xz  + ((size_t)b * S_ + s0) * (2 * I_) + I_ + i;
    short*       yp  = y16 + ((size_t)b * S_ + s0) * I_ + i;
    __syncthreads();

    float dtv = dtp[0], xcv = xcp[0];
    for (int s = 0; s < T_; ++s) {
        float dtn = 0.f, xcn = 0.f;
        if (s + 1 < T_) { dtn = dtp[(size_t)(s + 1) * I_]; xcn = xcp[(size_t)(s + 1) * I_]; }
        float4 Bv = *(const float4*)&Bsh[s][sub * 4];
        float4 Cv = *(const float4*)&Csh[s][sub * 4];
        float dx = dtv * xcv;
        float yv;
        {
            float dA0 = expf(dtv * a[0]);
            float dA1 = expf(dtv * a[1]);
            float dA2 = expf(dtv * a[2]);
            float dA3 = expf(dtv * a[3]);
            h[0] = fmaf(dA0, h[0], dx * Bv.x);
            h[1] = fmaf(dA1, h[1], dx * Bv.y);
            h[2] = fmaf(dA2, h[2], dx * Bv.z);
            h[3] = fmaf(dA3, h[3], dx * Bv.w);
            yv = h[0] * Cv.x;
            yv = fmaf(h[1], Cv.y, yv);
            yv = fmaf(h[2], Cv.z, yv);
            yv = fmaf(h[3], Cv.w, yv);
        }
        yv += __shfl_xor(yv, 1, 4);
        yv += __shfl_xor(yv, 2, 4);
        if (sub == 0) {
            float zv = zp[(size_t)s * (2 * I_)];
            yp[(size_t)s * I_] = f2bf((yv + xcv * Dv) * siluf(zv));
        }
        dtv = dtn; xcv = xcn;
    }
}

// ---------------------------------------------------------------------------
extern "C" void kernel_launch(void* const* d_in, const int* in_sizes, int n_in,
                              void* d_out, int out_size, void* d_ws, size_t ws_size,
                              hipStream_t stream)
{
    const float* x     = (const float*)d_in[0];
    const float* W_in  = (const float*)d_in[1];
    const float* b_in  = (const float*)d_in[2];
    const float* norm_w= (const float*)d_in[3];
    const float* ipw   = (const float*)d_in[4];
    const float* cw    = (const float*)d_in[5];
    const float* cb    = (const float*)d_in[6];
    const float* xpw   = (const float*)d_in[7];
    const float* dpw   = (const float*)d_in[8];
    const float* dpb   = (const float*)d_in[9];
    const float* A_log = (const float*)d_in[10];
    const float* Dp    = (const float*)d_in[11];
    const float* opw   = (const float*)d_in[12];
    const float* nfw   = (const float*)d_in[13];
    float* out = (float*)d_out;

    // fp32 scratch
    float* wsf  = (float*)d_ws;
    float* h    = wsf;  wsf += (size_t)MROWS * H_;
    float* xzb  = wsf;  wsf += (size_t)MROWS * 2 * I_;
    float* xcb  = wsf;  wsf += (size_t)MROWS * I_;
    float* dbcb = wsf;  wsf += (size_t)MROWS * 80;
    float* dtb  = wsf;  wsf += (size_t)MROWS * I_;
    float* Pb   = wsf;  wsf += (size_t)B_ * C_ * I_ * N_;
    float* heb  = wsf;  wsf += (size_t)B_ * C_ * I_ * N_;
    float* Hsb  = wsf;  wsf += (size_t)B_ * C_ * I_ * N_;
    float* dpwTf= wsf;  wsf += (size_t)L_ * I_ * R_;
    // bf16 scratch
    short* wss   = (short*)wsf;
    short* x_bf  = wss;  wss += (size_t)MROWS * CIN_;
    short* u_bf  = wss;  wss += (size_t)MROWS * H_;
    short* xc_bf = wss;  wss += (size_t)MROWS * I_;
    short* y_bf  = wss;  wss += (size_t)MROWS * I_;
    short* WinT  = wss;  wss += (size_t)H_ * CIN_;
    short* ipwT  = wss;  wss += (size_t)L_ * 2 * I_ * H_;
    short* xpwT  = wss;  wss += (size_t)L_ * 128 * I_;
    short* opwT  = wss;  wss += (size_t)L_ * H_ * I_;

    // split-K partial aliases (dead at use time):
    float* part_Win = dtb;   // 2*2048*768  <= 2048*1536
    float* part_x   = dtb;   // 8*2048*80   <= 2048*1536
    float* part_o   = xzb;   // 3*2048*768  <= 2048*3072

    const dim3 blk(256);
    const dim3 tblk(32, 8);

    // one-time conversions
    cast_bf16<<<(MROWS * CIN_ / 4 + 255) / 256, blk, 0, stream>>>(x, x_bf, MROWS * CIN_ / 4);
    wtrans<<<dim3(H_ / 32, CIN_ / 32), tblk, 0, stream>>>(W_in, WinT, CIN_, H_, CIN_, H_);
    for (int l = 0; l < L_; ++l) {
        wtrans<<<dim3(2 * I_ / 32, H_ / 32), tblk, 0, stream>>>(
            ipw + (size_t)l * H_ * 2 * I_, ipwT + (size_t)l * 2 * I_ * H_, H_, 2 * I_, H_, 2 * I_);
        wtrans<<<dim3(128 / 32, I_ / 32), tblk, 0, stream>>>(
            xpw + (size_t)l * I_ * 80, xpwT + (size_t)l * 128 * I_, I_, 80, I_, 128);
        wtrans<<<dim3(H_ / 32, I_ / 32), tblk, 0, stream>>>(
            opw + (size_t)l * I_ * H_, opwT + (size_t)l * H_ * I_, I_, H_, I_, H_);
        trans_f32<<<dim3(I_ / 32, 2), tblk, 0, stream>>>(
            dpw + (size_t)l * R_ * I_, dpwTf + (size_t)l * I_ * R_, R_, I_);
    }

    // h = x @ W_in + b_in   (split-K=2)
    gemm_mfma<<<dim3(H_ / 128, MROWS / 64, 2), blk, 0, stream>>>(
        x_bf, WinT, nullptr, part_Win, MROWS, H_, CIN_, CIN_, CIN_, H_, 0);
    reduce_parts<<<(MROWS * H_ + 255) / 256, blk, 0, stream>>>(
        part_Win, h, b_in, MROWS * H_, H_, 2, 1);

    const int scan_blocks = B_ * C_ * (I_ / 64);   // 1536

    for (int l = 0; l < L_; ++l) {
        rmsnorm_bf16<<<MROWS, blk, 0, stream>>>(h, norm_w + l * H_, u_bf, H_);
        gemm_mfma<<<dim3(2 * I_ / 128, MROWS / 64, 1), blk, 0, stream>>>(
            u_bf, ipwT + (size_t)l * 2 * I_ * H_, nullptr, xzb,
            MROWS, 2 * I_, H_, H_, H_, 2 * I_, 0);
        conv_silu_kernel<<<(MROWS * I_ + 255) / 256, blk, 0, stream>>>(
            xzb, cw + l * I_ * K_, cb + l * I_, xcb, xc_bf);
        gemm_mfma<<<dim3(1, MROWS / 64, 8), blk, 0, stream>>>(
            xc_bf, xpwT + (size_t)l * 128 * I_, nullptr, part_x,
            MROWS, 80, I_, I_, I_, 80, 0);
        reduce_parts<<<(MROWS * 80 + 255) / 256, blk, 0, stream>>>(
            part_x, dbcb, nullptr, MROWS * 80, 80, 8, 0);
        dt_kernel<<<dim3(I_ / 256, MROWS / DT_ROWS), blk, 0, stream>>>(
            dbcb, dpwTf + (size_t)l * I_ * R_, dpb + l * I_, dtb);
        // chunked selective scan (register-state)
        scan_pass1<<<scan_blocks, blk, 0, stream>>>(
            xcb, dtb, dbcb, A_log + l * I_ * N_, Pb, heb);
        scan_pass2<<<(B_ * I_ * N_ + 255) / 256, blk, 0, stream>>>(Pb, heb, Hsb);
        scan_pass3<<<scan_blocks, blk, 0, stream>>>(
            xcb, dtb, dbcb, xzb, A_log + l * I_ * N_, Dp + l * I_, Hsb, y_bf);
        gemm_mfma<<<dim3(H_ / 128, MROWS / 64, 3), blk, 0, stream>>>(
            y_bf, opwT + (size_t)l * H_ * I_, nullptr, part_o,
            MROWS, H_, I_, I_, I_, H_, 0);
        reduce_parts<<<(MROWS * H_ + 255) / 256, blk, 0, stream>>>(
            part_o, h, nullptr, MROWS * H_, H_, 3, 2);
    }

    rmsnorm_f32<<<MROWS, blk, 0, stream>>>(h, nfw, out, H_);
}